// Round 1
// baseline (615.938 us; speedup 1.0000x reference)
//
#include <hip/hip_runtime.h>
#include <hip/hip_bf16.h>

// GCN 2-layer: x[N,128] @ W1[128,64] -> agg(+relu) -> @ W2[64,32] -> agg -> out[N,32]
// CSR-by-dst built on device each call (deterministic work; fp sum order varies
// only within atomic-filled adjacency lists -> error ~1e-6, well under tolerance).

#define C_IN  128
#define C_HID 64
#define C_OUT 32

// ---------- CSR build ----------

__global__ void count_deg(const int* __restrict__ dst, int* __restrict__ deg, int E) {
    int idx = blockIdx.x * blockDim.x + threadIdx.x;
    int stride = gridDim.x * blockDim.x;
    for (int e = idx; e < E; e += stride)
        atomicAdd(&deg[dst[e]], 1);
}

__global__ void compute_dinv(const int* __restrict__ deg, float* __restrict__ dinv, int n) {
    int i = blockIdx.x * blockDim.x + threadIdx.x;
    if (i < n) dinv[i] = rsqrtf((float)deg[i] + 1.0f);
}

// block-level exclusive scan (1024 threads/block); writes per-block exclusive
// prefix into offsets and the block total into bsums[blockIdx].
__global__ void scan_blocks(const int* __restrict__ deg, int* __restrict__ offsets,
                            int* __restrict__ bsums, int n) {
    __shared__ int wsum[16];
    int tid = threadIdx.x, lane = tid & 63, wid = tid >> 6;
    int i = blockIdx.x * 1024 + tid;
    int v = (i < n) ? deg[i] : 0;
    int s = v;
    #pragma unroll
    for (int off = 1; off < 64; off <<= 1) {
        int t = __shfl_up(s, off, 64);
        if (lane >= off) s += t;
    }
    if (lane == 63) wsum[wid] = s;
    __syncthreads();
    if (wid == 0 && lane < 16) {
        int ws = wsum[lane];
        #pragma unroll
        for (int off = 1; off < 16; off <<= 1) {
            int t = __shfl_up(ws, off, 64);
            if (lane >= off) ws += t;
        }
        wsum[lane] = ws;                       // inclusive wave prefix
        if (lane == 15) bsums[blockIdx.x] = ws; // block total
    }
    __syncthreads();
    int wpre = (wid > 0) ? wsum[wid - 1] : 0;
    if (i < n) offsets[i] = wpre + s - v;       // exclusive within block
}

__global__ void scan_bsums(int* __restrict__ bsums, int nb) {
    if (blockIdx.x == 0 && threadIdx.x == 0) {
        int acc = 0;
        for (int b = 0; b < nb; ++b) { int t = bsums[b]; bsums[b] = acc; acc += t; }
    }
}

__global__ void scan_add(int* __restrict__ offsets, const int* __restrict__ bsums,
                         int n, int E) {
    int i = blockIdx.x * 1024 + threadIdx.x;
    if (i < n) offsets[i] += bsums[blockIdx.x];
    if (i == 0) offsets[n] = E;
}

__global__ void fill_csr(const int* __restrict__ src, const int* __restrict__ dst,
                         const int* __restrict__ offsets, int* __restrict__ cursor,
                         int* __restrict__ csr_src, int E) {
    int idx = blockIdx.x * blockDim.x + threadIdx.x;
    int stride = gridDim.x * blockDim.x;
    for (int e = idx; e < E; e += stride) {
        int d = dst[e];
        int pos = offsets[d] + atomicAdd(&cursor[d], 1);
        csr_src[pos] = src[e];
    }
}

// ---------- GEMMs (f32 vector ALU; weights in LDS) ----------

// xw[N,64] = x[N,128] @ W1[128,64]; one wave per row, lane = out col.
__global__ void gemm1(const float* __restrict__ x, const float* __restrict__ W1,
                      float* __restrict__ xw, int n) {
    __shared__ float Ws[C_IN * C_HID];  // 32 KiB
    for (int i = threadIdx.x; i < C_IN * C_HID; i += 256) Ws[i] = W1[i];
    __syncthreads();
    int wid = threadIdx.x >> 6, lane = threadIdx.x & 63;
    for (int row = blockIdx.x * 4 + wid; row < n; row += gridDim.x * 4) {
        const float4* xr = reinterpret_cast<const float4*>(x + (size_t)row * C_IN);
        float acc = 0.f;
        #pragma unroll
        for (int k4 = 0; k4 < C_IN / 4; ++k4) {
            float4 xv = xr[k4];
            int k = k4 * 4;
            acc += xv.x * Ws[(k + 0) * C_HID + lane];
            acc += xv.y * Ws[(k + 1) * C_HID + lane];
            acc += xv.z * Ws[(k + 2) * C_HID + lane];
            acc += xv.w * Ws[(k + 3) * C_HID + lane];
        }
        xw[(size_t)row * C_HID + lane] = acc;
    }
}

// xw2[N,32] = h[N,64] @ W2[64,32]; one wave handles 2 rows (half-wave each).
__global__ void gemm2(const float* __restrict__ h, const float* __restrict__ W2,
                      float* __restrict__ xw2, int n) {
    __shared__ float Ws[C_HID * C_OUT];  // 8 KiB
    for (int i = threadIdx.x; i < C_HID * C_OUT; i += 256) Ws[i] = W2[i];
    __syncthreads();
    int wid = threadIdx.x >> 6, lane = threadIdx.x & 63;
    int col = lane & 31, rh = lane >> 5;
    for (int base = (blockIdx.x * 4 + wid) * 2; base < n; base += gridDim.x * 8) {
        int row = base + rh;
        if (row >= n) continue;
        const float4* hr = reinterpret_cast<const float4*>(h + (size_t)row * C_HID);
        float acc = 0.f;
        #pragma unroll
        for (int k4 = 0; k4 < C_HID / 4; ++k4) {
            float4 hv = hr[k4];
            int k = k4 * 4;
            acc += hv.x * Ws[(k + 0) * C_OUT + col];
            acc += hv.y * Ws[(k + 1) * C_OUT + col];
            acc += hv.z * Ws[(k + 2) * C_OUT + col];
            acc += hv.w * Ws[(k + 3) * C_OUT + col];
        }
        xw2[(size_t)row * C_OUT + col] = acc;
    }
}

// ---------- Aggregations (CSR gather, one wave per node) ----------

// h[i,c] = relu(dinv_i * sum_{s in adj(i)} dinv_s * xw[s,c] + dinv_i^2 * xw[i,c] + b1[c])
__global__ void agg1(const float* __restrict__ xw, const float* __restrict__ dinv,
                     const int* __restrict__ offsets, const int* __restrict__ csr_src,
                     const float* __restrict__ b1, float* __restrict__ h, int n) {
    int wid = threadIdx.x >> 6, lane = threadIdx.x & 63;
    for (int i = blockIdx.x * 4 + wid; i < n; i += gridDim.x * 4) {
        int beg = offsets[i], end = offsets[i + 1];
        float di = dinv[i];
        float acc = 0.f;
        for (int k = beg; k < end; ++k) {
            int s = csr_src[k];
            acc += dinv[s] * xw[(size_t)s * C_HID + lane];
        }
        float v = di * acc + di * di * xw[(size_t)i * C_HID + lane] + b1[lane];
        h[(size_t)i * C_HID + lane] = fmaxf(v, 0.f);
    }
}

// out[i,c] = dinv_i * sum dinv_s * xw2[s,c] + dinv_i^2 * xw2[i,c] + b2[c]
// 32 channels: half-waves split the edge list, combine via shfl_xor(32).
__global__ void agg2(const float* __restrict__ xw2, const float* __restrict__ dinv,
                     const int* __restrict__ offsets, const int* __restrict__ csr_src,
                     const float* __restrict__ b2, float* __restrict__ out, int n) {
    int wid = threadIdx.x >> 6, lane = threadIdx.x & 63;
    int col = lane & 31, half = lane >> 5;
    for (int i = blockIdx.x * 4 + wid; i < n; i += gridDim.x * 4) {
        int beg = offsets[i], end = offsets[i + 1];
        float di = dinv[i];
        float acc = 0.f;
        for (int k = beg + half; k < end; k += 2) {
            int s = csr_src[k];
            acc += dinv[s] * xw2[(size_t)s * C_OUT + col];
        }
        acc += __shfl_xor(acc, 32, 64);
        if (half == 0) {
            float v = di * acc + di * di * xw2[(size_t)i * C_OUT + col] + b2[col];
            out[(size_t)i * C_OUT + col] = v;
        }
    }
}

extern "C" void kernel_launch(void* const* d_in, const int* in_sizes, int n_in,
                              void* d_out, int out_size, void* d_ws, size_t ws_size,
                              hipStream_t stream) {
    const float* x  = (const float*)d_in[0];
    const int*   ei = (const int*)d_in[1];
    const float* W1 = (const float*)d_in[2];
    const float* b1 = (const float*)d_in[3];
    const float* W2 = (const float*)d_in[4];
    const float* b2 = (const float*)d_in[5];
    float* out = (float*)d_out;

    const int N = in_sizes[0] / C_IN;      // 100000
    const int E = in_sizes[1] / 2;         // 1600000
    const int* src = ei;
    const int* dst = ei + E;

    // workspace layout (bytes)
    char* ws = (char*)d_ws;
    size_t off = 0;
    auto alloc = [&](size_t bytes) { char* p = ws + off; off += (bytes + 255) & ~(size_t)255; return p; };
    float* xw      = (float*)alloc((size_t)N * C_HID * 4);   // xw1, reused as xw2
    float* h       = (float*)alloc((size_t)N * C_HID * 4);
    int*   deg     = (int*)alloc((size_t)N * 4);
    float* dinv    = (float*)alloc((size_t)N * 4);
    int*   offsets = (int*)alloc((size_t)(N + 1) * 4);
    int*   cursor  = (int*)alloc((size_t)N * 4);
    int*   csr_src = (int*)alloc((size_t)E * 4);
    int*   bsums   = (int*)alloc(4096);
    (void)ws_size;

    const int nb1024 = (N + 1023) / 1024;  // 98

    hipMemsetAsync(deg, 0, (size_t)N * 4, stream);
    hipMemsetAsync(cursor, 0, (size_t)N * 4, stream);

    count_deg<<<2048, 256, 0, stream>>>(dst, deg, E);
    compute_dinv<<<(N + 255) / 256, 256, 0, stream>>>(deg, dinv, N);
    scan_blocks<<<nb1024, 1024, 0, stream>>>(deg, offsets, bsums, N);
    scan_bsums<<<1, 64, 0, stream>>>(bsums, nb1024);
    scan_add<<<nb1024, 1024, 0, stream>>>(offsets, bsums, N, E);
    fill_csr<<<2048, 256, 0, stream>>>(src, dst, offsets, cursor, csr_src, E);

    gemm1<<<2048, 256, 0, stream>>>(x, W1, xw, N);
    agg1<<<2048, 256, 0, stream>>>(xw, dinv, offsets, csr_src, b1, h, N);
    gemm2<<<2048, 256, 0, stream>>>(h, W2, xw, N);
    agg2<<<2048, 256, 0, stream>>>(xw, dinv, offsets, csr_src, b2, out, N);
}

// Round 2
// 487.450 us; speedup vs baseline: 1.2636x; 1.2636x over previous
//
#include <hip/hip_runtime.h>
#include <hip/hip_bf16.h>

// GCN 2-layer: x[N,128] @ W1[128,64] -> agg(+relu) -> @ W2[64,32] -> agg -> out[N,32]
// CSR-by-dst built on device each call. dinv folded into GEMM epilogue so agg
// kernels only gather pre-scaled rows: h_i = relu(d_i*(sum_s xws[s] + xws[i]) + b).

#define C_IN  128
#define C_HID 64
#define C_OUT 32

// ---------- CSR build ----------

__global__ void count_deg(const int* __restrict__ dst, int* __restrict__ deg, int E) {
    int idx = blockIdx.x * blockDim.x + threadIdx.x;
    int stride = gridDim.x * blockDim.x;
    for (int e = idx; e < E; e += stride)
        atomicAdd(&deg[dst[e]], 1);
}

__global__ void compute_dinv(const int* __restrict__ deg, float* __restrict__ dinv, int n) {
    int i = blockIdx.x * blockDim.x + threadIdx.x;
    if (i < n) dinv[i] = rsqrtf((float)deg[i] + 1.0f);
}

// block-level exclusive scan (1024 threads/block)
__global__ void scan_blocks(const int* __restrict__ deg, int* __restrict__ offsets,
                            int* __restrict__ bsums, int n) {
    __shared__ int wsum[16];
    int tid = threadIdx.x, lane = tid & 63, wid = tid >> 6;
    int i = blockIdx.x * 1024 + tid;
    int v = (i < n) ? deg[i] : 0;
    int s = v;
    #pragma unroll
    for (int off = 1; off < 64; off <<= 1) {
        int t = __shfl_up(s, off, 64);
        if (lane >= off) s += t;
    }
    if (lane == 63) wsum[wid] = s;
    __syncthreads();
    if (wid == 0 && lane < 16) {
        int ws = wsum[lane];
        #pragma unroll
        for (int off = 1; off < 16; off <<= 1) {
            int t = __shfl_up(ws, off, 64);
            if (lane >= off) ws += t;
        }
        wsum[lane] = ws;
        if (lane == 15) bsums[blockIdx.x] = ws;
    }
    __syncthreads();
    int wpre = (wid > 0) ? wsum[wid - 1] : 0;
    if (i < n) offsets[i] = wpre + s - v;
}

// parallel exclusive scan of block sums (nb <= 1024), one block
__global__ void scan_bsums(int* __restrict__ bsums, int nb) {
    __shared__ int wsum[16];
    int tid = threadIdx.x, lane = tid & 63, wid = tid >> 6;
    int v = (tid < nb) ? bsums[tid] : 0;
    int s = v;
    #pragma unroll
    for (int off = 1; off < 64; off <<= 1) {
        int t = __shfl_up(s, off, 64);
        if (lane >= off) s += t;
    }
    if (lane == 63) wsum[wid] = s;
    __syncthreads();
    if (wid == 0 && lane < 16) {
        int ws = wsum[lane];
        #pragma unroll
        for (int off = 1; off < 16; off <<= 1) {
            int t = __shfl_up(ws, off, 64);
            if (lane >= off) ws += t;
        }
        wsum[lane] = ws;
    }
    __syncthreads();
    int wpre = (wid > 0) ? wsum[wid - 1] : 0;
    if (tid < nb) bsums[tid] = wpre + s - v;
}

__global__ void scan_add(int* __restrict__ offsets, const int* __restrict__ bsums,
                         int n, int E) {
    int i = blockIdx.x * 1024 + threadIdx.x;
    if (i < n) offsets[i] += bsums[blockIdx.x];
    if (i == 0) offsets[n] = E;
}

__global__ void fill_csr(const int* __restrict__ src, const int* __restrict__ dst,
                         const int* __restrict__ offsets, int* __restrict__ cursor,
                         int* __restrict__ csr_src, int E) {
    int idx = blockIdx.x * blockDim.x + threadIdx.x;
    int stride = gridDim.x * blockDim.x;
    for (int e = idx; e < E; e += stride) {
        int d = dst[e];
        int pos = offsets[d] + atomicAdd(&cursor[d], 1);
        csr_src[pos] = src[e];
    }
}

// ---------- GEMMs (f32 vector ALU, register-blocked; dinv folded in) ----------

// xws[row,c] = dinv[row] * sum_k x[row,k] W1[k,c].  16 waves/block, 8 rows/wave.
__global__ __launch_bounds__(1024) void gemm1(
        const float* __restrict__ x, const float* __restrict__ W1,
        const float* __restrict__ dinv, float* __restrict__ xws, int n) {
    __shared__ float Ws[C_IN * C_HID];  // 32 KiB, shared by 16 waves
    for (int i = threadIdx.x; i < C_IN * C_HID; i += 1024) Ws[i] = W1[i];
    __syncthreads();
    int wid = threadIdx.x >> 6, lane = threadIdx.x & 63;
    int row0 = blockIdx.x * 128 + wid * 8;
    if (row0 >= n) return;
    float acc[8] = {0.f, 0.f, 0.f, 0.f, 0.f, 0.f, 0.f, 0.f};
    if (row0 + 8 <= n) {
        const float* xr = x + (size_t)row0 * C_IN;
        #pragma unroll 4
        for (int k4 = 0; k4 < C_IN / 4; ++k4) {
            int k = k4 * 4;
            float w0 = Ws[(k + 0) * C_HID + lane];
            float w1 = Ws[(k + 1) * C_HID + lane];
            float w2 = Ws[(k + 2) * C_HID + lane];
            float w3 = Ws[(k + 3) * C_HID + lane];
            #pragma unroll
            for (int r = 0; r < 8; ++r) {
                float4 xv = *reinterpret_cast<const float4*>(xr + (size_t)r * C_IN + k);
                acc[r] += xv.x * w0 + xv.y * w1 + xv.z * w2 + xv.w * w3;
            }
        }
        #pragma unroll
        for (int r = 0; r < 8; ++r)
            xws[(size_t)(row0 + r) * C_HID + lane] = dinv[row0 + r] * acc[r];
    } else {
        for (int r = 0; r < 8; ++r) {
            int row = row0 + r;
            if (row >= n) break;
            float a = 0.f;
            const float* xr = x + (size_t)row * C_IN;
            for (int k4 = 0; k4 < C_IN / 4; ++k4) {
                int k = k4 * 4;
                float4 xv = *reinterpret_cast<const float4*>(xr + k);
                a += xv.x * Ws[(k + 0) * C_HID + lane] + xv.y * Ws[(k + 1) * C_HID + lane]
                   + xv.z * Ws[(k + 2) * C_HID + lane] + xv.w * Ws[(k + 3) * C_HID + lane];
            }
            xws[(size_t)row * C_HID + lane] = dinv[row] * a;
        }
    }
}

// xws2[row,c] = dinv[row] * sum_k h[row,k] W2[k,c]. Split-K across half-waves.
__global__ __launch_bounds__(1024) void gemm2(
        const float* __restrict__ h, const float* __restrict__ W2,
        const float* __restrict__ dinv, float* __restrict__ xws2, int n) {
    __shared__ float Ws[C_HID * C_OUT];  // 8 KiB
    for (int i = threadIdx.x; i < C_HID * C_OUT; i += 1024) Ws[i] = W2[i];
    __syncthreads();
    int wid = threadIdx.x >> 6, lane = threadIdx.x & 63;
    int col = lane & 31, half = lane >> 5;
    int row0 = blockIdx.x * 128 + wid * 8;
    if (row0 >= n) return;
    float acc[8] = {0.f, 0.f, 0.f, 0.f, 0.f, 0.f, 0.f, 0.f};
    int rmax = min(8, n - row0);
    const float* hr = h + (size_t)row0 * C_HID + half * 32;  // this half's K range
    #pragma unroll 2
    for (int k4 = 0; k4 < 8; ++k4) {                          // 32 k per half
        int k = half * 32 + k4 * 4;
        float w0 = Ws[(k + 0) * C_OUT + col];
        float w1 = Ws[(k + 1) * C_OUT + col];
        float w2 = Ws[(k + 2) * C_OUT + col];
        float w3 = Ws[(k + 3) * C_OUT + col];
        for (int r = 0; r < rmax; ++r) {
            float4 hv = *reinterpret_cast<const float4*>(hr + (size_t)r * C_HID + k4 * 4);
            acc[r] += hv.x * w0 + hv.y * w1 + hv.z * w2 + hv.w * w3;
        }
    }
    #pragma unroll
    for (int r = 0; r < 8; ++r)
        acc[r] += __shfl_xor(acc[r], 32, 64);
    if (half == 0) {
        for (int r = 0; r < rmax; ++r)
            xws2[(size_t)(row0 + r) * C_OUT + col] = dinv[row0 + r] * acc[r];
    }
}

// ---------- Aggregations (CSR gather, one wave per node) ----------

// h[i,c] = relu(d_i * (sum_s xws[s,c] + xws[i,c]) + b1[c])
__global__ void agg1(const float* __restrict__ xws, const float* __restrict__ dinv,
                     const int* __restrict__ offsets, const int* __restrict__ csr_src,
                     const float* __restrict__ b1, float* __restrict__ h, int n) {
    int wid = threadIdx.x >> 6, lane = threadIdx.x & 63;
    float bias = b1[lane];
    for (int i = blockIdx.x * 4 + wid; i < n; i += gridDim.x * 4) {
        int beg = offsets[i], end = offsets[i + 1];
        float di = dinv[i];
        float acc = xws[(size_t)i * C_HID + lane];  // self-loop term
        int k = beg;
        for (; k + 4 <= end; k += 4) {
            int s0 = csr_src[k], s1 = csr_src[k + 1];
            int s2 = csr_src[k + 2], s3 = csr_src[k + 3];
            float a0 = xws[(size_t)s0 * C_HID + lane];
            float a1 = xws[(size_t)s1 * C_HID + lane];
            float a2 = xws[(size_t)s2 * C_HID + lane];
            float a3 = xws[(size_t)s3 * C_HID + lane];
            acc += (a0 + a1) + (a2 + a3);
        }
        for (; k < end; ++k)
            acc += xws[(size_t)csr_src[k] * C_HID + lane];
        h[(size_t)i * C_HID + lane] = fmaxf(di * acc + bias, 0.f);
    }
}

// out[i,c] = d_i * (sum_s xws2[s,c] + xws2[i,c]) + b2[c]; halves split edge list.
__global__ void agg2(const float* __restrict__ xws2, const float* __restrict__ dinv,
                     const int* __restrict__ offsets, const int* __restrict__ csr_src,
                     const float* __restrict__ b2, float* __restrict__ out, int n) {
    int wid = threadIdx.x >> 6, lane = threadIdx.x & 63;
    int col = lane & 31, half = lane >> 5;
    float bias = b2[col];
    for (int i = blockIdx.x * 4 + wid; i < n; i += gridDim.x * 4) {
        int beg = offsets[i], end = offsets[i + 1];
        int len = end - beg;
        int hlen = (len + 1) >> 1;
        int kb = beg + half * hlen;
        int ke = half ? end : (beg + hlen);
        float di = dinv[i];
        float acc = half ? 0.f : xws2[(size_t)i * C_OUT + col];  // self term once
        int k = kb;
        for (; k + 4 <= ke; k += 4) {
            int s0 = csr_src[k], s1 = csr_src[k + 1];
            int s2 = csr_src[k + 2], s3 = csr_src[k + 3];
            float a0 = xws2[(size_t)s0 * C_OUT + col];
            float a1 = xws2[(size_t)s1 * C_OUT + col];
            float a2 = xws2[(size_t)s2 * C_OUT + col];
            float a3 = xws2[(size_t)s3 * C_OUT + col];
            acc += (a0 + a1) + (a2 + a3);
        }
        for (; k < ke; ++k)
            acc += xws2[(size_t)csr_src[k] * C_OUT + col];
        acc += __shfl_xor(acc, 32, 64);
        if (half == 0)
            out[(size_t)i * C_OUT + col] = di * acc + bias;
    }
}

extern "C" void kernel_launch(void* const* d_in, const int* in_sizes, int n_in,
                              void* d_out, int out_size, void* d_ws, size_t ws_size,
                              hipStream_t stream) {
    const float* x  = (const float*)d_in[0];
    const int*   ei = (const int*)d_in[1];
    const float* W1 = (const float*)d_in[2];
    const float* b1 = (const float*)d_in[3];
    const float* W2 = (const float*)d_in[4];
    const float* b2 = (const float*)d_in[5];
    float* out = (float*)d_out;

    const int N = in_sizes[0] / C_IN;      // 100000
    const int E = in_sizes[1] / 2;         // 1600000
    const int* src = ei;
    const int* dst = ei + E;

    char* ws = (char*)d_ws;
    size_t off = 0;
    auto alloc = [&](size_t bytes) { char* p = ws + off; off += (bytes + 255) & ~(size_t)255; return p; };
    float* xw      = (float*)alloc((size_t)N * C_HID * 4);   // xws1, reused as xws2
    float* h       = (float*)alloc((size_t)N * C_HID * 4);
    int*   deg     = (int*)alloc((size_t)N * 4);
    float* dinv    = (float*)alloc((size_t)N * 4);
    int*   offsets = (int*)alloc((size_t)(N + 1) * 4);
    int*   cursor  = (int*)alloc((size_t)N * 4);
    int*   csr_src = (int*)alloc((size_t)E * 4);
    int*   bsums   = (int*)alloc(4096);
    (void)ws_size;

    const int nb1024 = (N + 1023) / 1024;  // 98

    hipMemsetAsync(deg, 0, (size_t)N * 4, stream);
    hipMemsetAsync(cursor, 0, (size_t)N * 4, stream);

    count_deg<<<2048, 256, 0, stream>>>(dst, deg, E);
    compute_dinv<<<(N + 255) / 256, 256, 0, stream>>>(deg, dinv, N);
    scan_blocks<<<nb1024, 1024, 0, stream>>>(deg, offsets, bsums, N);
    scan_bsums<<<1, 1024, 0, stream>>>(bsums, nb1024);
    scan_add<<<nb1024, 1024, 0, stream>>>(offsets, bsums, N, E);
    fill_csr<<<2048, 256, 0, stream>>>(src, dst, offsets, cursor, csr_src, E);

    const int gb1 = (N + 127) / 128;       // 782 blocks, 128 rows each
    gemm1<<<gb1, 1024, 0, stream>>>(x, W1, dinv, xw, N);
    agg1<<<2048, 256, 0, stream>>>(xw, dinv, offsets, csr_src, b1, h, N);
    gemm2<<<gb1, 1024, 0, stream>>>(h, W2, dinv, xw, N);
    agg2<<<2048, 256, 0, stream>>>(xw, dinv, offsets, csr_src, b2, out, N);
}

// Round 3
// 397.768 us; speedup vs baseline: 1.5485x; 1.2255x over previous
//
#include <hip/hip_runtime.h>
#include <hip/hip_bf16.h>

// GCN 2-layer: x[N,128] @ W1[128,64] -> agg(+relu) -> @ W2[64,32] -> agg -> out[N,32]
// CSR-by-dst built on device each call. dinv folded into GEMM epilogue so agg
// kernels only gather pre-scaled rows: h_i = relu(d_i*(sum_s xws[s] + xws[i]) + b).
// GEMMs: f32 vector-ALU, x-tile staged in LDS via coalesced float4 loads (vector
// memory path), W in LDS; inner loop reads W per-lane (2-way bank = free) and x
// as same-address broadcast b128 (conflict-free). Avoids the R1 pitfall where
// wave-uniform x addresses became s_loads serializing on lgkmcnt with ds_reads.

#define C_IN  128
#define C_HID 64
#define C_OUT 32

// ---------- CSR build ----------

__global__ void count_deg(const int* __restrict__ dst, int* __restrict__ deg, int E) {
    int idx = blockIdx.x * blockDim.x + threadIdx.x;
    int stride = gridDim.x * blockDim.x;
    for (int e = idx; e < E; e += stride)
        atomicAdd(&deg[dst[e]], 1);
}

__global__ void compute_dinv(const int* __restrict__ deg, float* __restrict__ dinv, int n) {
    int i = blockIdx.x * blockDim.x + threadIdx.x;
    if (i < n) dinv[i] = rsqrtf((float)deg[i] + 1.0f);
}

// block-level exclusive scan (1024 threads/block)
__global__ void scan_blocks(const int* __restrict__ deg, int* __restrict__ offsets,
                            int* __restrict__ bsums, int n) {
    __shared__ int wsum[16];
    int tid = threadIdx.x, lane = tid & 63, wid = tid >> 6;
    int i = blockIdx.x * 1024 + tid;
    int v = (i < n) ? deg[i] : 0;
    int s = v;
    #pragma unroll
    for (int off = 1; off < 64; off <<= 1) {
        int t = __shfl_up(s, off, 64);
        if (lane >= off) s += t;
    }
    if (lane == 63) wsum[wid] = s;
    __syncthreads();
    if (wid == 0 && lane < 16) {
        int ws = wsum[lane];
        #pragma unroll
        for (int off = 1; off < 16; off <<= 1) {
            int t = __shfl_up(ws, off, 64);
            if (lane >= off) ws += t;
        }
        wsum[lane] = ws;
        if (lane == 15) bsums[blockIdx.x] = ws;
    }
    __syncthreads();
    int wpre = (wid > 0) ? wsum[wid - 1] : 0;
    if (i < n) offsets[i] = wpre + s - v;
}

// parallel exclusive scan of block sums (nb <= 1024), one block
__global__ void scan_bsums(int* __restrict__ bsums, int nb) {
    __shared__ int wsum[16];
    int tid = threadIdx.x, lane = tid & 63, wid = tid >> 6;
    int v = (tid < nb) ? bsums[tid] : 0;
    int s = v;
    #pragma unroll
    for (int off = 1; off < 64; off <<= 1) {
        int t = __shfl_up(s, off, 64);
        if (lane >= off) s += t;
    }
    if (lane == 63) wsum[wid] = s;
    __syncthreads();
    if (wid == 0 && lane < 16) {
        int ws = wsum[lane];
        #pragma unroll
        for (int off = 1; off < 16; off <<= 1) {
            int t = __shfl_up(ws, off, 64);
            if (lane >= off) ws += t;
        }
        wsum[lane] = ws;
    }
    __syncthreads();
    int wpre = (wid > 0) ? wsum[wid - 1] : 0;
    if (tid < nb) bsums[tid] = wpre + s - v;
}

__global__ void scan_add(int* __restrict__ offsets, const int* __restrict__ bsums,
                         int n, int E) {
    int i = blockIdx.x * 1024 + threadIdx.x;
    if (i < n) offsets[i] += bsums[blockIdx.x];
    if (i == 0) offsets[n] = E;
}

// cursor pre-initialized to offsets (d2d copy); atomicAdd returns absolute pos.
__global__ void fill_csr(const int* __restrict__ src, const int* __restrict__ dst,
                         int* __restrict__ cursor, int* __restrict__ csr_src, int E) {
    int idx = blockIdx.x * blockDim.x + threadIdx.x;
    int stride = gridDim.x * blockDim.x;
    for (int e = idx; e < E; e += stride) {
        int pos = atomicAdd(&cursor[dst[e]], 1);
        csr_src[pos] = src[e];
    }
}

// ---------- GEMMs (f32, LDS-tiled) ----------

// xws[row,c] = dinv[row] * sum_k x[row,k] W1[k,c].
// 256 thr / 4 waves; 64-row tile in LDS; wave w -> rows w*16..w*16+15, lane = col.
__global__ __launch_bounds__(256) void gemm1(
        const float* __restrict__ x, const float* __restrict__ W1,
        const float* __restrict__ dinv, float* __restrict__ xws, int n) {
    __shared__ float Ws[C_IN * C_HID];   // 32 KiB
    __shared__ float Xs[64 * C_IN];      // 32 KiB
    int tid = threadIdx.x;
    {
        const float4* Wv = reinterpret_cast<const float4*>(W1);
        float4* Wsv = reinterpret_cast<float4*>(Ws);
        #pragma unroll
        for (int p = 0; p < (C_IN * C_HID / 4) / 256; ++p)   // 8 passes
            Wsv[p * 256 + tid] = Wv[p * 256 + tid];
    }
    int row0 = blockIdx.x * 64;
    {
        float4* Xsv = reinterpret_cast<float4*>(Xs);
        const float4* xv = reinterpret_cast<const float4*>(x + (size_t)row0 * C_IN);
        int maxv = min(64, n - row0) * (C_IN / 4);
        #pragma unroll
        for (int p = 0; p < 8; ++p) {
            int idx = p * 256 + tid;
            Xsv[idx] = (idx < maxv) ? xv[idx] : float4{0.f, 0.f, 0.f, 0.f};
        }
    }
    __syncthreads();
    int wid = tid >> 6, lane = tid & 63;
    int rbase = wid * 16;
    float acc[16];
    #pragma unroll
    for (int r = 0; r < 16; ++r) acc[r] = 0.f;
    const float4* Xsv = reinterpret_cast<const float4*>(Xs);
    #pragma unroll 2
    for (int k4 = 0; k4 < C_IN / 4; ++k4) {
        float w0 = Ws[(k4 * 4 + 0) * C_HID + lane];
        float w1 = Ws[(k4 * 4 + 1) * C_HID + lane];
        float w2 = Ws[(k4 * 4 + 2) * C_HID + lane];
        float w3 = Ws[(k4 * 4 + 3) * C_HID + lane];
        #pragma unroll
        for (int r = 0; r < 16; ++r) {
            float4 xv = Xsv[(rbase + r) * (C_IN / 4) + k4];  // broadcast read
            acc[r] += xv.x * w0 + xv.y * w1 + xv.z * w2 + xv.w * w3;
        }
    }
    #pragma unroll
    for (int r = 0; r < 16; ++r) {
        int row = row0 + rbase + r;
        if (row < n) xws[(size_t)row * C_HID + lane] = dinv[row] * acc[r];
    }
}

// xws2[row,c] = dinv[row] * sum_k h[row,k] W2[k,c].
// 256 thr / 4 waves; 128-row tile; wave w -> rows w*32..w*32+31 (half-wave = 16
// rows x 32 cols, full K); col = lane&31.
__global__ __launch_bounds__(256) void gemm2(
        const float* __restrict__ h, const float* __restrict__ W2,
        const float* __restrict__ dinv, float* __restrict__ xws2, int n) {
    __shared__ float Ws[C_HID * C_OUT];  // 8 KiB
    __shared__ float Hs[128 * C_HID];    // 32 KiB
    int tid = threadIdx.x;
    {
        const float4* Wv = reinterpret_cast<const float4*>(W2);
        float4* Wsv = reinterpret_cast<float4*>(Ws);
        #pragma unroll
        for (int p = 0; p < (C_HID * C_OUT / 4) / 256; ++p)  // 2 passes
            Wsv[p * 256 + tid] = Wv[p * 256 + tid];
    }
    int row0 = blockIdx.x * 128;
    {
        float4* Hsv = reinterpret_cast<float4*>(Hs);
        const float4* hv = reinterpret_cast<const float4*>(h + (size_t)row0 * C_HID);
        int maxv = min(128, n - row0) * (C_HID / 4);
        #pragma unroll
        for (int p = 0; p < 8; ++p) {
            int idx = p * 256 + tid;
            Hsv[idx] = (idx < maxv) ? hv[idx] : float4{0.f, 0.f, 0.f, 0.f};
        }
    }
    __syncthreads();
    int wid = tid >> 6, lane = tid & 63;
    int col = lane & 31, rh = lane >> 5;
    int rbase = wid * 32 + rh * 16;
    float acc[16];
    #pragma unroll
    for (int r = 0; r < 16; ++r) acc[r] = 0.f;
    const float4* Hsv = reinterpret_cast<const float4*>(Hs);
    #pragma unroll 2
    for (int k4 = 0; k4 < C_HID / 4; ++k4) {
        float w0 = Ws[(k4 * 4 + 0) * C_OUT + col];
        float w1 = Ws[(k4 * 4 + 1) * C_OUT + col];
        float w2 = Ws[(k4 * 4 + 2) * C_OUT + col];
        float w3 = Ws[(k4 * 4 + 3) * C_OUT + col];
        #pragma unroll
        for (int r = 0; r < 16; ++r) {
            float4 hv = Hsv[(rbase + r) * (C_HID / 4) + k4];  // 2-addr broadcast
            acc[r] += hv.x * w0 + hv.y * w1 + hv.z * w2 + hv.w * w3;
        }
    }
    #pragma unroll
    for (int r = 0; r < 16; ++r) {
        int row = row0 + rbase + r;
        if (row < n) xws2[(size_t)row * C_OUT + col] = dinv[row] * acc[r];
    }
}

// ---------- Aggregations (CSR gather, one wave per node) ----------

// h[i,c] = relu(d_i * (sum_s xws[s,c] + xws[i,c]) + b1[c])
__global__ void agg1(const float* __restrict__ xws, const float* __restrict__ dinv,
                     const int* __restrict__ offsets, const int* __restrict__ csr_src,
                     const float* __restrict__ b1, float* __restrict__ h, int n) {
    int wid = threadIdx.x >> 6, lane = threadIdx.x & 63;
    float bias = b1[lane];
    for (int i = blockIdx.x * 4 + wid; i < n; i += gridDim.x * 4) {
        int beg = offsets[i], end = offsets[i + 1];
        float di = dinv[i];
        float acc = xws[(size_t)i * C_HID + lane];  // self-loop term
        int k = beg;
        for (; k + 4 <= end; k += 4) {
            int s0 = csr_src[k], s1 = csr_src[k + 1];
            int s2 = csr_src[k + 2], s3 = csr_src[k + 3];
            float a0 = xws[(size_t)s0 * C_HID + lane];
            float a1 = xws[(size_t)s1 * C_HID + lane];
            float a2 = xws[(size_t)s2 * C_HID + lane];
            float a3 = xws[(size_t)s3 * C_HID + lane];
            acc += (a0 + a1) + (a2 + a3);
        }
        for (; k < end; ++k)
            acc += xws[(size_t)csr_src[k] * C_HID + lane];
        h[(size_t)i * C_HID + lane] = fmaxf(di * acc + bias, 0.f);
    }
}

// out[i,c] = d_i * (sum_s xws2[s,c] + xws2[i,c]) + b2[c]; halves split edge list.
__global__ void agg2(const float* __restrict__ xws2, const float* __restrict__ dinv,
                     const int* __restrict__ offsets, const int* __restrict__ csr_src,
                     const float* __restrict__ b2, float* __restrict__ out, int n) {
    int wid = threadIdx.x >> 6, lane = threadIdx.x & 63;
    int col = lane & 31, half = lane >> 5;
    float bias = b2[col];
    for (int i = blockIdx.x * 4 + wid; i < n; i += gridDim.x * 4) {
        int beg = offsets[i], end = offsets[i + 1];
        int len = end - beg;
        int hlen = (len + 1) >> 1;
        int kb = beg + half * hlen;
        int ke = half ? end : (beg + hlen);
        float di = dinv[i];
        float acc = half ? 0.f : xws2[(size_t)i * C_OUT + col];
        int k = kb;
        for (; k + 4 <= ke; k += 4) {
            int s0 = csr_src[k], s1 = csr_src[k + 1];
            int s2 = csr_src[k + 2], s3 = csr_src[k + 3];
            float a0 = xws2[(size_t)s0 * C_OUT + col];
            float a1 = xws2[(size_t)s1 * C_OUT + col];
            float a2 = xws2[(size_t)s2 * C_OUT + col];
            float a3 = xws2[(size_t)s3 * C_OUT + col];
            acc += (a0 + a1) + (a2 + a3);
        }
        for (; k < ke; ++k)
            acc += xws2[(size_t)csr_src[k] * C_OUT + col];
        acc += __shfl_xor(acc, 32, 64);
        if (half == 0)
            out[(size_t)i * C_OUT + col] = di * acc + bias;
    }
}

extern "C" void kernel_launch(void* const* d_in, const int* in_sizes, int n_in,
                              void* d_out, int out_size, void* d_ws, size_t ws_size,
                              hipStream_t stream) {
    const float* x  = (const float*)d_in[0];
    const int*   ei = (const int*)d_in[1];
    const float* W1 = (const float*)d_in[2];
    const float* b1 = (const float*)d_in[3];
    const float* W2 = (const float*)d_in[4];
    const float* b2 = (const float*)d_in[5];
    float* out = (float*)d_out;

    const int N = in_sizes[0] / C_IN;      // 100000
    const int E = in_sizes[1] / 2;         // 1600000
    const int* src = ei;
    const int* dst = ei + E;

    char* ws = (char*)d_ws;
    size_t off = 0;
    auto alloc = [&](size_t bytes) { char* p = ws + off; off += (bytes + 255) & ~(size_t)255; return p; };
    float* xw      = (float*)alloc((size_t)N * C_HID * 4);   // xws1, reused as xws2
    float* h       = (float*)alloc((size_t)N * C_HID * 4);
    int*   deg     = (int*)alloc((size_t)N * 4);
    float* dinv    = (float*)alloc((size_t)N * 4);
    int*   offsets = (int*)alloc((size_t)(N + 1) * 4);
    int*   cursor  = (int*)alloc((size_t)N * 4);
    int*   csr_src = (int*)alloc((size_t)E * 4);
    int*   bsums   = (int*)alloc(4096);
    (void)ws_size;

    const int nb1024 = (N + 1023) / 1024;  // 98

    hipMemsetAsync(deg, 0, (size_t)N * 4, stream);

    count_deg<<<2048, 256, 0, stream>>>(dst, deg, E);
    compute_dinv<<<(N + 255) / 256, 256, 0, stream>>>(deg, dinv, N);
    scan_blocks<<<nb1024, 1024, 0, stream>>>(deg, offsets, bsums, N);
    scan_bsums<<<1, 1024, 0, stream>>>(bsums, nb1024);
    scan_add<<<nb1024, 1024, 0, stream>>>(offsets, bsums, N, E);
    hipMemcpyAsync(cursor, offsets, (size_t)N * 4, hipMemcpyDeviceToDevice, stream);
    fill_csr<<<2048, 256, 0, stream>>>(src, dst, cursor, csr_src, E);

    gemm1<<<(N + 63) / 64, 256, 0, stream>>>(x, W1, dinv, xw, N);
    agg1<<<2048, 256, 0, stream>>>(xw, dinv, offsets, csr_src, b1, h, N);
    gemm2<<<(N + 127) / 128, 256, 0, stream>>>(h, W2, dinv, xw, N);
    agg2<<<2048, 256, 0, stream>>>(xw, dinv, offsets, csr_src, b2, out, N);
}

// Round 4
// 304.774 us; speedup vs baseline: 2.0210x; 1.3051x over previous
//
#include <hip/hip_runtime.h>
#include <hip/hip_bf16.h>

// GCN 2-layer: x[N,128] @ W1[128,64] -> agg(+relu) -> @ W2[64,32] -> agg -> out[N,32]
// CSR-by-dst built per call via a 2-level counting sort:
//   A) bucket_edges: partition edges into 1024-node dst buckets (LDS rank +
//      block reservation) -> bucket-major packed entries, coalesced-ish writes.
//      (R3 lesson: direct atomic scatter of 4B into 6.4MB = 107MB of partial-line
//      HBM writes, 131us. Bucketing confines writes to dense runs.)
//   B) fill_csr_bucketed: one block per bucket, node cursors in LDS, csr writes
//      land in a 64KB window -> full lines form in L2.
// dinv folded into GEMM epilogue; agg kernels gather pre-scaled rows.

#define C_IN  128
#define C_HID 64
#define C_OUT 32
#define BK_SHIFT 10
#define BK_NODES (1 << BK_SHIFT)
#define BK_MAXB  128

// ---------- CSR build ----------

__global__ void count_deg(const int* __restrict__ dst, int* __restrict__ deg, int E) {
    int idx = blockIdx.x * blockDim.x + threadIdx.x;
    int stride = gridDim.x * blockDim.x;
    for (int e = idx; e < E; e += stride)
        atomicAdd(&deg[dst[e]], 1);
}

// Phase A: bucket partition + fused degree count. 4096 edges/block.
__global__ __launch_bounds__(256) void bucket_edges(
        const int* __restrict__ src, const int* __restrict__ dst,
        int* __restrict__ deg, int* __restrict__ bcur,
        unsigned int* __restrict__ bucketed, int cap, int E, int nb) {
    __shared__ int cnt[BK_MAXB];
    __shared__ int base[BK_MAXB];
    int tid = threadIdx.x;
    for (int i = tid; i < nb; i += 256) cnt[i] = 0;
    __syncthreads();
    int e0 = blockIdx.x * 4096;
    int myb[16]; int myr[16]; unsigned int mys[16];
    #pragma unroll
    for (int i = 0; i < 16; ++i) {
        int e = e0 + i * 256 + tid;
        if (e < E) {
            int d = dst[e];
            int s = src[e];
            atomicAdd(&deg[d], 1);
            int b = d >> BK_SHIFT;
            myb[i] = b;
            mys[i] = (unsigned int)s | ((unsigned int)(d & (BK_NODES - 1)) << 17);
            myr[i] = atomicAdd(&cnt[b], 1);
        } else myb[i] = -1;
    }
    __syncthreads();
    for (int i = tid; i < nb; i += 256)
        base[i] = atomicAdd(&bcur[i], cnt[i]);
    __syncthreads();
    #pragma unroll
    for (int i = 0; i < 16; ++i) {
        if (myb[i] >= 0) {
            int pos = base[myb[i]] + myr[i];
            if (pos < cap)
                bucketed[(size_t)myb[i] * cap + pos] = mys[i];
        }
    }
}

// Phase B: one block per bucket; LDS node cursors; writes confined to the
// bucket's csr window.
__global__ __launch_bounds__(512) void fill_csr_bucketed(
        const unsigned int* __restrict__ bucketed, const int* __restrict__ bcur,
        const int* __restrict__ offsets, int* __restrict__ csr_src, int cap, int n) {
    __shared__ int lcur[BK_NODES];
    int b = blockIdx.x;
    int node0 = b << BK_SHIFT;
    int nn = min(BK_NODES, n - node0);
    for (int j = threadIdx.x; j < nn; j += 512)
        lcur[j] = offsets[node0 + j];
    __syncthreads();
    int cnt = bcur[b];
    if (cnt > cap) cnt = cap;
    const unsigned int* bp = bucketed + (size_t)b * cap;
    for (int e = threadIdx.x; e < cnt; e += 512) {
        unsigned int v = bp[e];
        int s = (int)(v & 0x1FFFFu);
        int dl = (int)(v >> 17);
        int pos = atomicAdd(&lcur[dl], 1);
        csr_src[pos] = s;
    }
}

__global__ void compute_dinv(const int* __restrict__ deg, float* __restrict__ dinv, int n) {
    int i = blockIdx.x * blockDim.x + threadIdx.x;
    if (i < n) dinv[i] = rsqrtf((float)deg[i] + 1.0f);
}

// block-level exclusive scan (1024 threads/block)
__global__ void scan_blocks(const int* __restrict__ deg, int* __restrict__ offsets,
                            int* __restrict__ bsums, int n) {
    __shared__ int wsum[16];
    int tid = threadIdx.x, lane = tid & 63, wid = tid >> 6;
    int i = blockIdx.x * 1024 + tid;
    int v = (i < n) ? deg[i] : 0;
    int s = v;
    #pragma unroll
    for (int off = 1; off < 64; off <<= 1) {
        int t = __shfl_up(s, off, 64);
        if (lane >= off) s += t;
    }
    if (lane == 63) wsum[wid] = s;
    __syncthreads();
    if (wid == 0 && lane < 16) {
        int ws = wsum[lane];
        #pragma unroll
        for (int off = 1; off < 16; off <<= 1) {
            int t = __shfl_up(ws, off, 64);
            if (lane >= off) ws += t;
        }
        wsum[lane] = ws;
        if (lane == 15) bsums[blockIdx.x] = ws;
    }
    __syncthreads();
    int wpre = (wid > 0) ? wsum[wid - 1] : 0;
    if (i < n) offsets[i] = wpre + s - v;
}

// parallel exclusive scan of block sums (nb <= 1024), one block
__global__ void scan_bsums(int* __restrict__ bsums, int nb) {
    __shared__ int wsum[16];
    int tid = threadIdx.x, lane = tid & 63, wid = tid >> 6;
    int v = (tid < nb) ? bsums[tid] : 0;
    int s = v;
    #pragma unroll
    for (int off = 1; off < 64; off <<= 1) {
        int t = __shfl_up(s, off, 64);
        if (lane >= off) s += t;
    }
    if (lane == 63) wsum[wid] = s;
    __syncthreads();
    if (wid == 0 && lane < 16) {
        int ws = wsum[lane];
        #pragma unroll
        for (int off = 1; off < 16; off <<= 1) {
            int t = __shfl_up(ws, off, 64);
            if (lane >= off) ws += t;
        }
        wsum[lane] = ws;
    }
    __syncthreads();
    int wpre = (wid > 0) ? wsum[wid - 1] : 0;
    if (tid < nb) bsums[tid] = wpre + s - v;
}

__global__ void scan_add(int* __restrict__ offsets, const int* __restrict__ bsums,
                         int n, int E) {
    int i = blockIdx.x * 1024 + threadIdx.x;
    if (i < n) offsets[i] += bsums[blockIdx.x];
    if (i == 0) offsets[n] = E;
}

// fallback: cursor pre-initialized to offsets; atomicAdd returns absolute pos.
__global__ void fill_csr(const int* __restrict__ src, const int* __restrict__ dst,
                         int* __restrict__ cursor, int* __restrict__ csr_src, int E) {
    int idx = blockIdx.x * blockDim.x + threadIdx.x;
    int stride = gridDim.x * blockDim.x;
    for (int e = idx; e < E; e += stride) {
        int pos = atomicAdd(&cursor[dst[e]], 1);
        csr_src[pos] = src[e];
    }
}

// ---------- GEMMs (f32, LDS-tiled) ----------

__global__ __launch_bounds__(256) void gemm1(
        const float* __restrict__ x, const float* __restrict__ W1,
        const float* __restrict__ dinv, float* __restrict__ xws, int n) {
    __shared__ float Ws[C_IN * C_HID];   // 32 KiB
    __shared__ float Xs[64 * C_IN];      // 32 KiB
    int tid = threadIdx.x;
    {
        const float4* Wv = reinterpret_cast<const float4*>(W1);
        float4* Wsv = reinterpret_cast<float4*>(Ws);
        #pragma unroll
        for (int p = 0; p < (C_IN * C_HID / 4) / 256; ++p)
            Wsv[p * 256 + tid] = Wv[p * 256 + tid];
    }
    int row0 = blockIdx.x * 64;
    {
        float4* Xsv = reinterpret_cast<float4*>(Xs);
        const float4* xv = reinterpret_cast<const float4*>(x + (size_t)row0 * C_IN);
        int maxv = min(64, n - row0) * (C_IN / 4);
        #pragma unroll
        for (int p = 0; p < 8; ++p) {
            int idx = p * 256 + tid;
            Xsv[idx] = (idx < maxv) ? xv[idx] : float4{0.f, 0.f, 0.f, 0.f};
        }
    }
    __syncthreads();
    int wid = tid >> 6, lane = tid & 63;
    int rbase = wid * 16;
    float acc[16];
    #pragma unroll
    for (int r = 0; r < 16; ++r) acc[r] = 0.f;
    const float4* Xsv = reinterpret_cast<const float4*>(Xs);
    #pragma unroll 2
    for (int k4 = 0; k4 < C_IN / 4; ++k4) {
        float w0 = Ws[(k4 * 4 + 0) * C_HID + lane];
        float w1 = Ws[(k4 * 4 + 1) * C_HID + lane];
        float w2 = Ws[(k4 * 4 + 2) * C_HID + lane];
        float w3 = Ws[(k4 * 4 + 3) * C_HID + lane];
        #pragma unroll
        for (int r = 0; r < 16; ++r) {
            float4 xv = Xsv[(rbase + r) * (C_IN / 4) + k4];  // broadcast read
            acc[r] += xv.x * w0 + xv.y * w1 + xv.z * w2 + xv.w * w3;
        }
    }
    #pragma unroll
    for (int r = 0; r < 16; ++r) {
        int row = row0 + rbase + r;
        if (row < n) xws[(size_t)row * C_HID + lane] = dinv[row] * acc[r];
    }
}

__global__ __launch_bounds__(256) void gemm2(
        const float* __restrict__ h, const float* __restrict__ W2,
        const float* __restrict__ dinv, float* __restrict__ xws2, int n) {
    __shared__ float Ws[C_HID * C_OUT];  // 8 KiB
    __shared__ float Hs[128 * C_HID];    // 32 KiB
    int tid = threadIdx.x;
    {
        const float4* Wv = reinterpret_cast<const float4*>(W2);
        float4* Wsv = reinterpret_cast<float4*>(Ws);
        #pragma unroll
        for (int p = 0; p < (C_HID * C_OUT / 4) / 256; ++p)
            Wsv[p * 256 + tid] = Wv[p * 256 + tid];
    }
    int row0 = blockIdx.x * 128;
    {
        float4* Hsv = reinterpret_cast<float4*>(Hs);
        const float4* hv = reinterpret_cast<const float4*>(h + (size_t)row0 * C_HID);
        int maxv = min(128, n - row0) * (C_HID / 4);
        #pragma unroll
        for (int p = 0; p < 8; ++p) {
            int idx = p * 256 + tid;
            Hsv[idx] = (idx < maxv) ? hv[idx] : float4{0.f, 0.f, 0.f, 0.f};
        }
    }
    __syncthreads();
    int wid = tid >> 6, lane = tid & 63;
    int col = lane & 31, rh = lane >> 5;
    int rbase = wid * 32 + rh * 16;
    float acc[16];
    #pragma unroll
    for (int r = 0; r < 16; ++r) acc[r] = 0.f;
    const float4* Hsv = reinterpret_cast<const float4*>(Hs);
    #pragma unroll 2
    for (int k4 = 0; k4 < C_HID / 4; ++k4) {
        float w0 = Ws[(k4 * 4 + 0) * C_OUT + col];
        float w1 = Ws[(k4 * 4 + 1) * C_OUT + col];
        float w2 = Ws[(k4 * 4 + 2) * C_OUT + col];
        float w3 = Ws[(k4 * 4 + 3) * C_OUT + col];
        #pragma unroll
        for (int r = 0; r < 16; ++r) {
            float4 hv = Hsv[(rbase + r) * (C_HID / 4) + k4];
            acc[r] += hv.x * w0 + hv.y * w1 + hv.z * w2 + hv.w * w3;
        }
    }
    #pragma unroll
    for (int r = 0; r < 16; ++r) {
        int row = row0 + rbase + r;
        if (row < n) xws2[(size_t)row * C_OUT + col] = dinv[row] * acc[r];
    }
}

// ---------- Aggregations (CSR gather, one wave per node) ----------

__global__ void agg1(const float* __restrict__ xws, const float* __restrict__ dinv,
                     const int* __restrict__ offsets, const int* __restrict__ csr_src,
                     const float* __restrict__ b1, float* __restrict__ h, int n) {
    int wid = threadIdx.x >> 6, lane = threadIdx.x & 63;
    float bias = b1[lane];
    for (int i = blockIdx.x * 4 + wid; i < n; i += gridDim.x * 4) {
        int beg = offsets[i], end = offsets[i + 1];
        float di = dinv[i];
        float acc = xws[(size_t)i * C_HID + lane];  // self-loop term
        int k = beg;
        for (; k + 4 <= end; k += 4) {
            int s0 = csr_src[k], s1 = csr_src[k + 1];
            int s2 = csr_src[k + 2], s3 = csr_src[k + 3];
            float a0 = xws[(size_t)s0 * C_HID + lane];
            float a1 = xws[(size_t)s1 * C_HID + lane];
            float a2 = xws[(size_t)s2 * C_HID + lane];
            float a3 = xws[(size_t)s3 * C_HID + lane];
            acc += (a0 + a1) + (a2 + a3);
        }
        for (; k < end; ++k)
            acc += xws[(size_t)csr_src[k] * C_HID + lane];
        h[(size_t)i * C_HID + lane] = fmaxf(di * acc + bias, 0.f);
    }
}

__global__ void agg2(const float* __restrict__ xws2, const float* __restrict__ dinv,
                     const int* __restrict__ offsets, const int* __restrict__ csr_src,
                     const float* __restrict__ b2, float* __restrict__ out, int n) {
    int wid = threadIdx.x >> 6, lane = threadIdx.x & 63;
    int col = lane & 31, half = lane >> 5;
    float bias = b2[col];
    for (int i = blockIdx.x * 4 + wid; i < n; i += gridDim.x * 4) {
        int beg = offsets[i], end = offsets[i + 1];
        int len = end - beg;
        int hlen = (len + 1) >> 1;
        int kb = beg + half * hlen;
        int ke = half ? end : (beg + hlen);
        float di = dinv[i];
        float acc = half ? 0.f : xws2[(size_t)i * C_OUT + col];
        int k = kb;
        for (; k + 4 <= ke; k += 4) {
            int s0 = csr_src[k], s1 = csr_src[k + 1];
            int s2 = csr_src[k + 2], s3 = csr_src[k + 3];
            float a0 = xws2[(size_t)s0 * C_OUT + col];
            float a1 = xws2[(size_t)s1 * C_OUT + col];
            float a2 = xws2[(size_t)s2 * C_OUT + col];
            float a3 = xws2[(size_t)s3 * C_OUT + col];
            acc += (a0 + a1) + (a2 + a3);
        }
        for (; k < ke; ++k)
            acc += xws2[(size_t)csr_src[k] * C_OUT + col];
        acc += __shfl_xor(acc, 32, 64);
        if (half == 0)
            out[(size_t)i * C_OUT + col] = di * acc + bias;
    }
}

extern "C" void kernel_launch(void* const* d_in, const int* in_sizes, int n_in,
                              void* d_out, int out_size, void* d_ws, size_t ws_size,
                              hipStream_t stream) {
    const float* x  = (const float*)d_in[0];
    const int*   ei = (const int*)d_in[1];
    const float* W1 = (const float*)d_in[2];
    const float* b1 = (const float*)d_in[3];
    const float* W2 = (const float*)d_in[4];
    const float* b2 = (const float*)d_in[5];
    float* out = (float*)d_out;

    const int N = in_sizes[0] / C_IN;      // 100000
    const int E = in_sizes[1] / 2;         // 1600000
    const int* src = ei;
    const int* dst = ei + E;

    const int NB = (N + BK_NODES - 1) >> BK_SHIFT;          // 98
    const int CAP = (2 * (E / NB) + 1023) & ~1023;          // 32768 (2x mean)

    char* ws = (char*)d_ws;
    size_t off = 0;
    auto alloc = [&](size_t bytes) { char* p = ws + off; off += (bytes + 255) & ~(size_t)255; return p; };
    float* xw      = (float*)alloc((size_t)N * C_HID * 4);
    float* h       = (float*)alloc((size_t)N * C_HID * 4);
    int*   deg     = (int*)alloc((size_t)N * 4);
    float* dinv    = (float*)alloc((size_t)N * 4);
    int*   offsets = (int*)alloc((size_t)(N + 1) * 4);
    int*   cursor  = (int*)alloc((size_t)N * 4);
    int*   csr_src = (int*)alloc((size_t)E * 4);
    int*   bsums   = (int*)alloc(4096);
    int*   bcur    = (int*)alloc((size_t)BK_MAXB * 4);
    unsigned int* bucketed = (unsigned int*)alloc((size_t)NB * CAP * 4);
    bool use_bucket = (off <= ws_size) && (NB <= BK_MAXB) && (N < (1 << 17));

    const int nb1024 = (N + 1023) / 1024;  // 98

    hipMemsetAsync(deg, 0, (size_t)N * 4, stream);

    if (use_bucket) {
        hipMemsetAsync(bcur, 0, (size_t)NB * 4, stream);
        bucket_edges<<<(E + 4095) / 4096, 256, 0, stream>>>(
            src, dst, deg, bcur, bucketed, CAP, E, NB);
        compute_dinv<<<(N + 255) / 256, 256, 0, stream>>>(deg, dinv, N);
        scan_blocks<<<nb1024, 1024, 0, stream>>>(deg, offsets, bsums, N);
        scan_bsums<<<1, 1024, 0, stream>>>(bsums, nb1024);
        scan_add<<<nb1024, 1024, 0, stream>>>(offsets, bsums, N, E);
        fill_csr_bucketed<<<NB, 512, 0, stream>>>(bucketed, bcur, offsets, csr_src, CAP, N);
    } else {
        count_deg<<<2048, 256, 0, stream>>>(dst, deg, E);
        compute_dinv<<<(N + 255) / 256, 256, 0, stream>>>(deg, dinv, N);
        scan_blocks<<<nb1024, 1024, 0, stream>>>(deg, offsets, bsums, N);
        scan_bsums<<<1, 1024, 0, stream>>>(bsums, nb1024);
        scan_add<<<nb1024, 1024, 0, stream>>>(offsets, bsums, N, E);
        hipMemcpyAsync(cursor, offsets, (size_t)N * 4, hipMemcpyDeviceToDevice, stream);
        fill_csr<<<2048, 256, 0, stream>>>(src, dst, cursor, csr_src, E);
    }

    gemm1<<<(N + 63) / 64, 256, 0, stream>>>(x, W1, dinv, xw, N);
    agg1<<<2048, 256, 0, stream>>>(xw, dinv, offsets, csr_src, b1, h, N);
    gemm2<<<(N + 127) / 128, 256, 0, stream>>>(h, W2, dinv, xw, N);
    agg2<<<2048, 256, 0, stream>>>(xw, dinv, offsets, csr_src, b2, out, N);
}

// Round 5
// 250.126 us; speedup vs baseline: 2.4625x; 1.2185x over previous
//
#include <hip/hip_runtime.h>
#include <hip/hip_bf16.h>

// GCN 2-layer: x[N,128] @ W1[128,64] -> agg(+relu) -> @ W2[64,32] -> agg -> out[N,32]
// CSR-by-dst built per call via 2-level counting sort:
//   A) bucket_edges: LDS-staged, bucket-sorted block partition -> COALESCED run
//      writes into bucket-major array. (R4 lesson: rank-order scattered 4B stores
//      cost ~32B HBM each; staging + sequential copy-out forms full lines.)
//   B1) bucket_deg: per-bucket LDS histogram -> coalesced deg writes (no global atomics).
//   B2) fill_csr_bucketed: per-bucket LDS cursors, csr writes land in 64KB window.
// dinv folded into GEMM epilogue; agg kernels gather pre-scaled rows.

#define C_IN  128
#define C_HID 64
#define C_OUT 32
#define BK_SHIFT 10
#define BK_NODES (1 << BK_SHIFT)
#define BK_MAXB  128
#define EPB 2048   // edges per bucket_edges block

// ---------- CSR build ----------

// Phase A: partition edges into 1024-node dst buckets, bucket-major packed.
__global__ __launch_bounds__(256) void bucket_edges(
        const int* __restrict__ src, const int* __restrict__ dst,
        int* __restrict__ bcur, unsigned int* __restrict__ bucketed,
        int cap, int E, int nb) {
    __shared__ unsigned int stage[EPB];     // 8 KiB, entries sorted by bucket
    __shared__ unsigned char bkt[EPB];      // 2 KiB, bucket id per staged slot
    __shared__ int cnt[BK_MAXB];
    __shared__ int lofs[BK_MAXB];
    __shared__ int base[BK_MAXB];
    int tid = threadIdx.x;
    for (int i = tid; i < nb; i += 256) cnt[i] = 0;
    __syncthreads();
    int e0 = blockIdx.x * EPB;
    int myb[8]; int myr[8]; unsigned int mys[8];
    #pragma unroll
    for (int i = 0; i < 8; ++i) {
        int e = e0 + i * 256 + tid;
        if (e < E) {
            int d = dst[e];
            int s = src[e];
            int b = d >> BK_SHIFT;
            myb[i] = b;
            mys[i] = (unsigned int)s | ((unsigned int)(d & (BK_NODES - 1)) << 17);
            myr[i] = atomicAdd(&cnt[b], 1);
        } else myb[i] = -1;
    }
    __syncthreads();
    // exclusive scan of cnt[0..nb) by wave 0; each lane owns buckets 2l, 2l+1
    if (tid < 64) {
        int b0 = 2 * tid, b1 = 2 * tid + 1;
        int c0 = (b0 < nb) ? cnt[b0] : 0;
        int c1 = (b1 < nb) ? cnt[b1] : 0;
        int p = c0 + c1;
        int s = p;
        #pragma unroll
        for (int off = 1; off < 64; off <<= 1) {
            int t = __shfl_up(s, off, 64);
            if (tid >= off) s += t;
        }
        if (b0 < nb) lofs[b0] = s - p;       // exclusive prefix
        if (b1 < nb) lofs[b1] = s - c1;
    }
    __syncthreads();
    // scatter into LDS stage, bucket-sorted
    #pragma unroll
    for (int i = 0; i < 8; ++i) {
        if (myb[i] >= 0) {
            int p = lofs[myb[i]] + myr[i];
            stage[p] = mys[i];
            bkt[p] = (unsigned char)myb[i];
        }
    }
    // reserve global space: one atomic per (block,bucket)
    for (int i = tid; i < nb; i += 256)
        base[i] = atomicAdd(&bcur[i], cnt[i]);
    __syncthreads();
    // coalesced copy-out: consecutive p -> consecutive global within each run
    int total = min(EPB, E - e0);
    for (int p = tid; p < total; p += 256) {
        int b = bkt[p];
        int di = base[b] + (p - lofs[b]);
        if (di < cap)
            bucketed[(size_t)b * cap + di] = stage[p];
    }
}

// Phase B1: per-bucket degree histogram in LDS -> coalesced deg writes.
__global__ __launch_bounds__(1024) void bucket_deg(
        const unsigned int* __restrict__ bucketed, const int* __restrict__ bcur,
        int* __restrict__ deg, int cap, int n) {
    __shared__ int lcur[BK_NODES];
    int b = blockIdx.x;
    int node0 = b << BK_SHIFT;
    int nn = min(BK_NODES, n - node0);
    for (int j = threadIdx.x; j < BK_NODES; j += 1024) lcur[j] = 0;
    __syncthreads();
    int cnt = min(bcur[b], cap);
    const unsigned int* bp = bucketed + (size_t)b * cap;
    for (int e = threadIdx.x; e < cnt; e += 1024)
        atomicAdd(&lcur[bp[e] >> 17], 1);
    __syncthreads();
    for (int j = threadIdx.x; j < nn; j += 1024)
        deg[node0 + j] = lcur[j];
}

// Phase B2: one block per bucket; LDS node cursors; writes confined to window.
__global__ __launch_bounds__(1024) void fill_csr_bucketed(
        const unsigned int* __restrict__ bucketed, const int* __restrict__ bcur,
        const int* __restrict__ offsets, int* __restrict__ csr_src, int cap, int n) {
    __shared__ int lcur[BK_NODES];
    int b = blockIdx.x;
    int node0 = b << BK_SHIFT;
    int nn = min(BK_NODES, n - node0);
    for (int j = threadIdx.x; j < nn; j += 1024)
        lcur[j] = offsets[node0 + j];
    __syncthreads();
    int cnt = min(bcur[b], cap);
    const unsigned int* bp = bucketed + (size_t)b * cap;
    for (int e = threadIdx.x; e < cnt; e += 1024) {
        unsigned int v = bp[e];
        int pos = atomicAdd(&lcur[v >> 17], 1);
        csr_src[pos] = (int)(v & 0x1FFFFu);
    }
}

// fallback path kernels
__global__ void count_deg(const int* __restrict__ dst, int* __restrict__ deg, int E) {
    int idx = blockIdx.x * blockDim.x + threadIdx.x;
    int stride = gridDim.x * blockDim.x;
    for (int e = idx; e < E; e += stride)
        atomicAdd(&deg[dst[e]], 1);
}

__global__ void fill_csr(const int* __restrict__ src, const int* __restrict__ dst,
                         int* __restrict__ cursor, int* __restrict__ csr_src, int E) {
    int idx = blockIdx.x * blockDim.x + threadIdx.x;
    int stride = gridDim.x * blockDim.x;
    for (int e = idx; e < E; e += stride) {
        int pos = atomicAdd(&cursor[dst[e]], 1);
        csr_src[pos] = src[e];
    }
}

// block-level exclusive scan (1024 threads/block); also emits dinv = rsqrt(deg+1)
__global__ void scan_blocks(const int* __restrict__ deg, int* __restrict__ offsets,
                            int* __restrict__ bsums, float* __restrict__ dinv, int n) {
    __shared__ int wsum[16];
    int tid = threadIdx.x, lane = tid & 63, wid = tid >> 6;
    int i = blockIdx.x * 1024 + tid;
    int v = (i < n) ? deg[i] : 0;
    if (i < n) dinv[i] = rsqrtf((float)v + 1.0f);
    int s = v;
    #pragma unroll
    for (int off = 1; off < 64; off <<= 1) {
        int t = __shfl_up(s, off, 64);
        if (lane >= off) s += t;
    }
    if (lane == 63) wsum[wid] = s;
    __syncthreads();
    if (wid == 0 && lane < 16) {
        int ws = wsum[lane];
        #pragma unroll
        for (int off = 1; off < 16; off <<= 1) {
            int t = __shfl_up(ws, off, 64);
            if (lane >= off) ws += t;
        }
        wsum[lane] = ws;
        if (lane == 15) bsums[blockIdx.x] = ws;
    }
    __syncthreads();
    int wpre = (wid > 0) ? wsum[wid - 1] : 0;
    if (i < n) offsets[i] = wpre + s - v;
}

// parallel exclusive scan of block sums (nb <= 1024), one block
__global__ void scan_bsums(int* __restrict__ bsums, int nb) {
    __shared__ int wsum[16];
    int tid = threadIdx.x, lane = tid & 63, wid = tid >> 6;
    int v = (tid < nb) ? bsums[tid] : 0;
    int s = v;
    #pragma unroll
    for (int off = 1; off < 64; off <<= 1) {
        int t = __shfl_up(s, off, 64);
        if (lane >= off) s += t;
    }
    if (lane == 63) wsum[wid] = s;
    __syncthreads();
    if (wid == 0 && lane < 16) {
        int ws = wsum[lane];
        #pragma unroll
        for (int off = 1; off < 16; off <<= 1) {
            int t = __shfl_up(ws, off, 64);
            if (lane >= off) ws += t;
        }
        wsum[lane] = ws;
    }
    __syncthreads();
    int wpre = (wid > 0) ? wsum[wid - 1] : 0;
    if (tid < nb) bsums[tid] = wpre + s - v;
}

__global__ void scan_add(int* __restrict__ offsets, const int* __restrict__ bsums,
                         int n, int E) {
    int i = blockIdx.x * 1024 + threadIdx.x;
    if (i < n) offsets[i] += bsums[blockIdx.x];
    if (i == 0) offsets[n] = E;
}

// ---------- GEMMs (f32, LDS-tiled) ----------

__global__ __launch_bounds__(256) void gemm1(
        const float* __restrict__ x, const float* __restrict__ W1,
        const float* __restrict__ dinv, float* __restrict__ xws, int n) {
    __shared__ float Ws[C_IN * C_HID];   // 32 KiB
    __shared__ float Xs[64 * C_IN];      // 32 KiB
    int tid = threadIdx.x;
    {
        const float4* Wv = reinterpret_cast<const float4*>(W1);
        float4* Wsv = reinterpret_cast<float4*>(Ws);
        #pragma unroll
        for (int p = 0; p < (C_IN * C_HID / 4) / 256; ++p)
            Wsv[p * 256 + tid] = Wv[p * 256 + tid];
    }
    int row0 = blockIdx.x * 64;
    {
        float4* Xsv = reinterpret_cast<float4*>(Xs);
        const float4* xv = reinterpret_cast<const float4*>(x + (size_t)row0 * C_IN);
        int maxv = min(64, n - row0) * (C_IN / 4);
        #pragma unroll
        for (int p = 0; p < 8; ++p) {
            int idx = p * 256 + tid;
            Xsv[idx] = (idx < maxv) ? xv[idx] : float4{0.f, 0.f, 0.f, 0.f};
        }
    }
    __syncthreads();
    int wid = tid >> 6, lane = tid & 63;
    int rbase = wid * 16;
    float acc[16];
    #pragma unroll
    for (int r = 0; r < 16; ++r) acc[r] = 0.f;
    const float4* Xsv = reinterpret_cast<const float4*>(Xs);
    #pragma unroll 2
    for (int k4 = 0; k4 < C_IN / 4; ++k4) {
        float w0 = Ws[(k4 * 4 + 0) * C_HID + lane];
        float w1 = Ws[(k4 * 4 + 1) * C_HID + lane];
        float w2 = Ws[(k4 * 4 + 2) * C_HID + lane];
        float w3 = Ws[(k4 * 4 + 3) * C_HID + lane];
        #pragma unroll
        for (int r = 0; r < 16; ++r) {
            float4 xv = Xsv[(rbase + r) * (C_IN / 4) + k4];  // broadcast read
            acc[r] += xv.x * w0 + xv.y * w1 + xv.z * w2 + xv.w * w3;
        }
    }
    #pragma unroll
    for (int r = 0; r < 16; ++r) {
        int row = row0 + rbase + r;
        if (row < n) xws[(size_t)row * C_HID + lane] = dinv[row] * acc[r];
    }
}

__global__ __launch_bounds__(256) void gemm2(
        const float* __restrict__ h, const float* __restrict__ W2,
        const float* __restrict__ dinv, float* __restrict__ xws2, int n) {
    __shared__ float Ws[C_HID * C_OUT];  // 8 KiB
    __shared__ float Hs[128 * C_HID];    // 32 KiB
    int tid = threadIdx.x;
    {
        const float4* Wv = reinterpret_cast<const float4*>(W2);
        float4* Wsv = reinterpret_cast<float4*>(Ws);
        #pragma unroll
        for (int p = 0; p < (C_HID * C_OUT / 4) / 256; ++p)
            Wsv[p * 256 + tid] = Wv[p * 256 + tid];
    }
    int row0 = blockIdx.x * 128;
    {
        float4* Hsv = reinterpret_cast<float4*>(Hs);
        const float4* hv = reinterpret_cast<const float4*>(h + (size_t)row0 * C_HID);
        int maxv = min(128, n - row0) * (C_HID / 4);
        #pragma unroll
        for (int p = 0; p < 8; ++p) {
            int idx = p * 256 + tid;
            Hsv[idx] = (idx < maxv) ? hv[idx] : float4{0.f, 0.f, 0.f, 0.f};
        }
    }
    __syncthreads();
    int wid = tid >> 6, lane = tid & 63;
    int col = lane & 31, rh = lane >> 5;
    int rbase = wid * 32 + rh * 16;
    float acc[16];
    #pragma unroll
    for (int r = 0; r < 16; ++r) acc[r] = 0.f;
    const float4* Hsv = reinterpret_cast<const float4*>(Hs);
    #pragma unroll 2
    for (int k4 = 0; k4 < C_HID / 4; ++k4) {
        float w0 = Ws[(k4 * 4 + 0) * C_OUT + col];
        float w1 = Ws[(k4 * 4 + 1) * C_OUT + col];
        float w2 = Ws[(k4 * 4 + 2) * C_OUT + col];
        float w3 = Ws[(k4 * 4 + 3) * C_OUT + col];
        #pragma unroll
        for (int r = 0; r < 16; ++r) {
            float4 hv = Hsv[(rbase + r) * (C_HID / 4) + k4];
            acc[r] += hv.x * w0 + hv.y * w1 + hv.z * w2 + hv.w * w3;
        }
    }
    #pragma unroll
    for (int r = 0; r < 16; ++r) {
        int row = row0 + rbase + r;
        if (row < n) xws2[(size_t)row * C_OUT + col] = dinv[row] * acc[r];
    }
}

// ---------- Aggregations (CSR gather, one wave per node) ----------

__global__ void agg1(const float* __restrict__ xws, const float* __restrict__ dinv,
                     const int* __restrict__ offsets, const int* __restrict__ csr_src,
                     const float* __restrict__ b1, float* __restrict__ h, int n) {
    int wid = threadIdx.x >> 6, lane = threadIdx.x & 63;
    float bias = b1[lane];
    for (int i = blockIdx.x * 4 + wid; i < n; i += gridDim.x * 4) {
        int beg = offsets[i], end = offsets[i + 1];
        float di = dinv[i];
        float acc = xws[(size_t)i * C_HID + lane];  // self-loop term
        int k = beg;
        for (; k + 4 <= end; k += 4) {
            int s0 = csr_src[k], s1 = csr_src[k + 1];
            int s2 = csr_src[k + 2], s3 = csr_src[k + 3];
            float a0 = xws[(size_t)s0 * C_HID + lane];
            float a1 = xws[(size_t)s1 * C_HID + lane];
            float a2 = xws[(size_t)s2 * C_HID + lane];
            float a3 = xws[(size_t)s3 * C_HID + lane];
            acc += (a0 + a1) + (a2 + a3);
        }
        for (; k < end; ++k)
            acc += xws[(size_t)csr_src[k] * C_HID + lane];
        h[(size_t)i * C_HID + lane] = fmaxf(di * acc + bias, 0.f);
    }
}

__global__ void agg2(const float* __restrict__ xws2, const float* __restrict__ dinv,
                     const int* __restrict__ offsets, const int* __restrict__ csr_src,
                     const float* __restrict__ b2, float* __restrict__ out, int n) {
    int wid = threadIdx.x >> 6, lane = threadIdx.x & 63;
    int col = lane & 31, half = lane >> 5;
    float bias = b2[col];
    for (int i = blockIdx.x * 4 + wid; i < n; i += gridDim.x * 4) {
        int beg = offsets[i], end = offsets[i + 1];
        int len = end - beg;
        int hlen = (len + 1) >> 1;
        int kb = beg + half * hlen;
        int ke = half ? end : (beg + hlen);
        float di = dinv[i];
        float acc = half ? 0.f : xws2[(size_t)i * C_OUT + col];
        int k = kb;
        for (; k + 4 <= ke; k += 4) {
            int s0 = csr_src[k], s1 = csr_src[k + 1];
            int s2 = csr_src[k + 2], s3 = csr_src[k + 3];
            float a0 = xws2[(size_t)s0 * C_OUT + col];
            float a1 = xws2[(size_t)s1 * C_OUT + col];
            float a2 = xws2[(size_t)s2 * C_OUT + col];
            float a3 = xws2[(size_t)s3 * C_OUT + col];
            acc += (a0 + a1) + (a2 + a3);
        }
        for (; k < ke; ++k)
            acc += xws2[(size_t)csr_src[k] * C_OUT + col];
        acc += __shfl_xor(acc, 32, 64);
        if (half == 0)
            out[(size_t)i * C_OUT + col] = di * acc + bias;
    }
}

extern "C" void kernel_launch(void* const* d_in, const int* in_sizes, int n_in,
                              void* d_out, int out_size, void* d_ws, size_t ws_size,
                              hipStream_t stream) {
    const float* x  = (const float*)d_in[0];
    const int*   ei = (const int*)d_in[1];
    const float* W1 = (const float*)d_in[2];
    const float* b1 = (const float*)d_in[3];
    const float* W2 = (const float*)d_in[4];
    const float* b2 = (const float*)d_in[5];
    float* out = (float*)d_out;

    const int N = in_sizes[0] / C_IN;      // 100000
    const int E = in_sizes[1] / 2;         // 1600000
    const int* src = ei;
    const int* dst = ei + E;

    const int NB = (N + BK_NODES - 1) >> BK_SHIFT;          // 98
    const int CAP = (2 * (E / NB) + 1023) & ~1023;          // 32768 (2x mean)

    char* ws = (char*)d_ws;
    size_t off = 0;
    auto alloc = [&](size_t bytes) { char* p = ws + off; off += (bytes + 255) & ~(size_t)255; return p; };
    float* xw      = (float*)alloc((size_t)N * C_HID * 4);
    float* h       = (float*)alloc((size_t)N * C_HID * 4);
    int*   deg     = (int*)alloc((size_t)N * 4);
    float* dinv    = (float*)alloc((size_t)N * 4);
    int*   offsets = (int*)alloc((size_t)(N + 1) * 4);
    int*   cursor  = (int*)alloc((size_t)N * 4);
    int*   csr_src = (int*)alloc((size_t)E * 4);
    int*   bsums   = (int*)alloc(4096);
    int*   bcur    = (int*)alloc((size_t)BK_MAXB * 4);
    unsigned int* bucketed = (unsigned int*)alloc((size_t)NB * CAP * 4);
    bool use_bucket = (off <= ws_size) && (NB <= BK_MAXB) && (N < (1 << 17));

    const int nb1024 = (N + 1023) / 1024;  // 98

    if (use_bucket) {
        hipMemsetAsync(bcur, 0, (size_t)NB * 4, stream);
        bucket_edges<<<(E + EPB - 1) / EPB, 256, 0, stream>>>(
            src, dst, bcur, bucketed, CAP, E, NB);
        bucket_deg<<<NB, 1024, 0, stream>>>(bucketed, bcur, deg, CAP, N);
        scan_blocks<<<nb1024, 1024, 0, stream>>>(deg, offsets, bsums, dinv, N);
        scan_bsums<<<1, 1024, 0, stream>>>(bsums, nb1024);
        scan_add<<<nb1024, 1024, 0, stream>>>(offsets, bsums, N, E);
        fill_csr_bucketed<<<NB, 1024, 0, stream>>>(bucketed, bcur, offsets, csr_src, CAP, N);
    } else {
        hipMemsetAsync(deg, 0, (size_t)N * 4, stream);
        count_deg<<<2048, 256, 0, stream>>>(dst, deg, E);
        scan_blocks<<<nb1024, 1024, 0, stream>>>(deg, offsets, bsums, dinv, N);
        scan_bsums<<<1, 1024, 0, stream>>>(bsums, nb1024);
        scan_add<<<nb1024, 1024, 0, stream>>>(offsets, bsums, N, E);
        hipMemcpyAsync(cursor, offsets, (size_t)N * 4, hipMemcpyDeviceToDevice, stream);
        fill_csr<<<2048, 256, 0, stream>>>(src, dst, cursor, csr_src, E);
    }

    gemm1<<<(N + 63) / 64, 256, 0, stream>>>(x, W1, dinv, xw, N);
    agg1<<<2048, 256, 0, stream>>>(xw, dinv, offsets, csr_src, b1, h, N);
    gemm2<<<(N + 127) / 128, 256, 0, stream>>>(h, W2, dinv, xw, N);
    agg2<<<2048, 256, 0, stream>>>(xw, dinv, offsets, csr_src, b2, out, N);
}

// Round 6
// 226.959 us; speedup vs baseline: 2.7139x; 1.1021x over previous
//
#include <hip/hip_runtime.h>
#include <hip/hip_bf16.h>

// GCN 2-layer: x[N,128] @ W1[128,64] -> agg(+relu) -> @ W2[64,32] -> agg -> out[N,32]
// CSR-by-dst via 2-level counting sort (R4/R5: staged, coalesced writes).
// R6: intermediates (xws, h, xws2) stored as bf16 (compute/accum stays f32) to
// halve the random-gather traffic in agg1/agg2; gemm1 at 512thr/8 waves to lift
// occupancy past the 64KB-LDS cap (R5: 17.6% occ was the gemm1 limiter).

#define C_IN  128
#define C_HID 64
#define C_OUT 32
#define BK_SHIFT 10
#define BK_NODES (1 << BK_SHIFT)
#define BK_MAXB  128
#define EPB 2048   // edges per bucket_edges block

typedef unsigned short ushort_t;

__device__ inline ushort_t f2bf(float f) {
    __hip_bfloat16 b = __float2bfloat16(f);   // RNE
    return *reinterpret_cast<ushort_t*>(&b);
}
__device__ inline float bf2f(ushort_t u) {
    return __uint_as_float((unsigned int)u << 16);
}

// ---------- CSR build ----------

// Phase A: partition edges into 1024-node dst buckets, bucket-major packed.
__global__ __launch_bounds__(256) void bucket_edges(
        const int* __restrict__ src, const int* __restrict__ dst,
        int* __restrict__ bcur, unsigned int* __restrict__ bucketed,
        int cap, int E, int nb) {
    __shared__ unsigned int stage[EPB];
    __shared__ unsigned char bkt[EPB];
    __shared__ int cnt[BK_MAXB];
    __shared__ int lofs[BK_MAXB];
    __shared__ int base[BK_MAXB];
    int tid = threadIdx.x;
    for (int i = tid; i < nb; i += 256) cnt[i] = 0;
    __syncthreads();
    int e0 = blockIdx.x * EPB;
    int myb[8]; int myr[8]; unsigned int mys[8];
    #pragma unroll
    for (int i = 0; i < 8; ++i) {
        int e = e0 + i * 256 + tid;
        if (e < E) {
            int d = dst[e];
            int s = src[e];
            int b = d >> BK_SHIFT;
            myb[i] = b;
            mys[i] = (unsigned int)s | ((unsigned int)(d & (BK_NODES - 1)) << 17);
            myr[i] = atomicAdd(&cnt[b], 1);
        } else myb[i] = -1;
    }
    __syncthreads();
    if (tid < 64) {
        int b0 = 2 * tid, b1 = 2 * tid + 1;
        int c0 = (b0 < nb) ? cnt[b0] : 0;
        int c1 = (b1 < nb) ? cnt[b1] : 0;
        int p = c0 + c1;
        int s = p;
        #pragma unroll
        for (int off = 1; off < 64; off <<= 1) {
            int t = __shfl_up(s, off, 64);
            if (tid >= off) s += t;
        }
        if (b0 < nb) lofs[b0] = s - p;
        if (b1 < nb) lofs[b1] = s - c1;
    }
    __syncthreads();
    #pragma unroll
    for (int i = 0; i < 8; ++i) {
        if (myb[i] >= 0) {
            int p = lofs[myb[i]] + myr[i];
            stage[p] = mys[i];
            bkt[p] = (unsigned char)myb[i];
        }
    }
    for (int i = tid; i < nb; i += 256)
        base[i] = atomicAdd(&bcur[i], cnt[i]);
    __syncthreads();
    int total = min(EPB, E - e0);
    for (int p = tid; p < total; p += 256) {
        int b = bkt[p];
        int di = base[b] + (p - lofs[b]);
        if (di < cap)
            bucketed[(size_t)b * cap + di] = stage[p];
    }
}

// Phase B1: per-bucket degree histogram in LDS -> coalesced deg writes.
__global__ __launch_bounds__(1024) void bucket_deg(
        const unsigned int* __restrict__ bucketed, const int* __restrict__ bcur,
        int* __restrict__ deg, int cap, int n) {
    __shared__ int lcur[BK_NODES];
    int b = blockIdx.x;
    int node0 = b << BK_SHIFT;
    int nn = min(BK_NODES, n - node0);
    for (int j = threadIdx.x; j < BK_NODES; j += 1024) lcur[j] = 0;
    __syncthreads();
    int cnt = min(bcur[b], cap);
    const unsigned int* bp = bucketed + (size_t)b * cap;
    for (int e = threadIdx.x; e < cnt; e += 1024)
        atomicAdd(&lcur[bp[e] >> 17], 1);
    __syncthreads();
    for (int j = threadIdx.x; j < nn; j += 1024)
        deg[node0 + j] = lcur[j];
}

// Phase B2: one block per bucket; LDS node cursors; writes confined to window.
__global__ __launch_bounds__(1024) void fill_csr_bucketed(
        const unsigned int* __restrict__ bucketed, const int* __restrict__ bcur,
        const int* __restrict__ offsets, int* __restrict__ csr_src, int cap, int n) {
    __shared__ int lcur[BK_NODES];
    int b = blockIdx.x;
    int node0 = b << BK_SHIFT;
    int nn = min(BK_NODES, n - node0);
    for (int j = threadIdx.x; j < nn; j += 1024)
        lcur[j] = offsets[node0 + j];
    __syncthreads();
    int cnt = min(bcur[b], cap);
    const unsigned int* bp = bucketed + (size_t)b * cap;
    for (int e = threadIdx.x; e < cnt; e += 1024) {
        unsigned int v = bp[e];
        int pos = atomicAdd(&lcur[v >> 17], 1);
        csr_src[pos] = (int)(v & 0x1FFFFu);
    }
}

// fallback path kernels
__global__ void count_deg(const int* __restrict__ dst, int* __restrict__ deg, int E) {
    int idx = blockIdx.x * blockDim.x + threadIdx.x;
    int stride = gridDim.x * blockDim.x;
    for (int e = idx; e < E; e += stride)
        atomicAdd(&deg[dst[e]], 1);
}

__global__ void fill_csr(const int* __restrict__ src, const int* __restrict__ dst,
                         int* __restrict__ cursor, int* __restrict__ csr_src, int E) {
    int idx = blockIdx.x * blockDim.x + threadIdx.x;
    int stride = gridDim.x * blockDim.x;
    for (int e = idx; e < E; e += stride) {
        int pos = atomicAdd(&cursor[dst[e]], 1);
        csr_src[pos] = src[e];
    }
}

// block-level exclusive scan; also emits dinv = rsqrt(deg+1)
__global__ void scan_blocks(const int* __restrict__ deg, int* __restrict__ offsets,
                            int* __restrict__ bsums, float* __restrict__ dinv, int n) {
    __shared__ int wsum[16];
    int tid = threadIdx.x, lane = tid & 63, wid = tid >> 6;
    int i = blockIdx.x * 1024 + tid;
    int v = (i < n) ? deg[i] : 0;
    if (i < n) dinv[i] = rsqrtf((float)v + 1.0f);
    int s = v;
    #pragma unroll
    for (int off = 1; off < 64; off <<= 1) {
        int t = __shfl_up(s, off, 64);
        if (lane >= off) s += t;
    }
    if (lane == 63) wsum[wid] = s;
    __syncthreads();
    if (wid == 0 && lane < 16) {
        int ws = wsum[lane];
        #pragma unroll
        for (int off = 1; off < 16; off <<= 1) {
            int t = __shfl_up(ws, off, 64);
            if (lane >= off) ws += t;
        }
        wsum[lane] = ws;
        if (lane == 15) bsums[blockIdx.x] = ws;
    }
    __syncthreads();
    int wpre = (wid > 0) ? wsum[wid - 1] : 0;
    if (i < n) offsets[i] = wpre + s - v;
}

__global__ void scan_bsums(int* __restrict__ bsums, int nb) {
    __shared__ int wsum[16];
    int tid = threadIdx.x, lane = tid & 63, wid = tid >> 6;
    int v = (tid < nb) ? bsums[tid] : 0;
    int s = v;
    #pragma unroll
    for (int off = 1; off < 64; off <<= 1) {
        int t = __shfl_up(s, off, 64);
        if (lane >= off) s += t;
    }
    if (lane == 63) wsum[wid] = s;
    __syncthreads();
    if (wid == 0 && lane < 16) {
        int ws = wsum[lane];
        #pragma unroll
        for (int off = 1; off < 16; off <<= 1) {
            int t = __shfl_up(ws, off, 64);
            if (lane >= off) ws += t;
        }
        wsum[lane] = ws;
    }
    __syncthreads();
    int wpre = (wid > 0) ? wsum[wid - 1] : 0;
    if (tid < nb) bsums[tid] = wpre + s - v;
}

__global__ void scan_add(int* __restrict__ offsets, const int* __restrict__ bsums,
                         int n, int E) {
    int i = blockIdx.x * 1024 + threadIdx.x;
    if (i < n) offsets[i] += bsums[blockIdx.x];
    if (i == 0) offsets[n] = E;
}

// ---------- GEMMs (f32 compute, LDS-tiled; bf16 outputs) ----------

// xws_bf[row,c] = bf16( dinv[row] * sum_k x[row,k] W1[k,c] )
// 512 thr / 8 waves; 64-row tile; wave w -> rows w*8..w*8+7, lane = col.
__global__ __launch_bounds__(512) void gemm1(
        const float* __restrict__ x, const float* __restrict__ W1,
        const float* __restrict__ dinv, ushort_t* __restrict__ xws_bf, int n) {
    __shared__ float Ws[C_IN * C_HID];   // 32 KiB
    __shared__ float Xs[64 * C_IN];      // 32 KiB
    int tid = threadIdx.x;
    {
        const float4* Wv = reinterpret_cast<const float4*>(W1);
        float4* Wsv = reinterpret_cast<float4*>(Ws);
        #pragma unroll
        for (int p = 0; p < (C_IN * C_HID / 4) / 512; ++p)   // 4 passes
            Wsv[p * 512 + tid] = Wv[p * 512 + tid];
    }
    int row0 = blockIdx.x * 64;
    {
        float4* Xsv = reinterpret_cast<float4*>(Xs);
        const float4* xv = reinterpret_cast<const float4*>(x + (size_t)row0 * C_IN);
        int maxv = min(64, n - row0) * (C_IN / 4);
        #pragma unroll
        for (int p = 0; p < 4; ++p) {
            int idx = p * 512 + tid;
            Xsv[idx] = (idx < maxv) ? xv[idx] : float4{0.f, 0.f, 0.f, 0.f};
        }
    }
    __syncthreads();
    int wid = tid >> 6, lane = tid & 63;
    int rbase = wid * 8;
    float acc[8];
    #pragma unroll
    for (int r = 0; r < 8; ++r) acc[r] = 0.f;
    const float4* Xsv = reinterpret_cast<const float4*>(Xs);
    #pragma unroll 2
    for (int k4 = 0; k4 < C_IN / 4; ++k4) {
        float w0 = Ws[(k4 * 4 + 0) * C_HID + lane];
        float w1 = Ws[(k4 * 4 + 1) * C_HID + lane];
        float w2 = Ws[(k4 * 4 + 2) * C_HID + lane];
        float w3 = Ws[(k4 * 4 + 3) * C_HID + lane];
        #pragma unroll
        for (int r = 0; r < 8; ++r) {
            float4 xv = Xsv[(rbase + r) * (C_IN / 4) + k4];  // broadcast read
            acc[r] += xv.x * w0 + xv.y * w1 + xv.z * w2 + xv.w * w3;
        }
    }
    #pragma unroll
    for (int r = 0; r < 8; ++r) {
        int row = row0 + rbase + r;
        if (row < n) xws_bf[(size_t)row * C_HID + lane] = f2bf(dinv[row] * acc[r]);
    }
}

// xws2_bf[row,c] = bf16( dinv[row] * sum_k h[row,k] W2[k,c] ); h read as bf16,
// stage-converted to f32 in LDS so the inner loop stays pure FMA.
__global__ __launch_bounds__(256) void gemm2(
        const ushort_t* __restrict__ h_bf, const float* __restrict__ W2,
        const float* __restrict__ dinv, ushort_t* __restrict__ xws2_bf, int n) {
    __shared__ float Ws[C_HID * C_OUT];  // 8 KiB
    __shared__ float Hs[128 * C_HID];    // 32 KiB
    int tid = threadIdx.x;
    {
        const float4* Wv = reinterpret_cast<const float4*>(W2);
        float4* Wsv = reinterpret_cast<float4*>(Ws);
        #pragma unroll
        for (int p = 0; p < (C_HID * C_OUT / 4) / 256; ++p)  // 2 passes
            Wsv[p * 256 + tid] = Wv[p * 256 + tid];
    }
    int row0 = blockIdx.x * 128;
    {
        // 128 rows x 64 bf16 = 8192 elems = 1024 x ushort8(16B); 4 per thread
        const uint4* hv = reinterpret_cast<const uint4*>(h_bf + (size_t)row0 * C_HID);
        float4* Hsv = reinterpret_cast<float4*>(Hs);
        int maxe = min(128, n - row0) * (C_HID / 8);   // in ushort8 units
        #pragma unroll
        for (int p = 0; p < 4; ++p) {
            int idx = p * 256 + tid;
            uint4 raw = (idx < maxe) ? hv[idx] : uint4{0u, 0u, 0u, 0u};
            float4 lo, hi;
            lo.x = bf2f((ushort_t)(raw.x & 0xffffu)); lo.y = bf2f((ushort_t)(raw.x >> 16));
            lo.z = bf2f((ushort_t)(raw.y & 0xffffu)); lo.w = bf2f((ushort_t)(raw.y >> 16));
            hi.x = bf2f((ushort_t)(raw.z & 0xffffu)); hi.y = bf2f((ushort_t)(raw.z >> 16));
            hi.z = bf2f((ushort_t)(raw.w & 0xffffu)); hi.w = bf2f((ushort_t)(raw.w >> 16));
            Hsv[idx * 2] = lo;
            Hsv[idx * 2 + 1] = hi;
        }
    }
    __syncthreads();
    int wid = tid >> 6, lane = tid & 63;
    int col = lane & 31, rh = lane >> 5;
    int rbase = wid * 32 + rh * 16;
    float acc[16];
    #pragma unroll
    for (int r = 0; r < 16; ++r) acc[r] = 0.f;
    const float4* Hsv = reinterpret_cast<const float4*>(Hs);
    #pragma unroll 2
    for (int k4 = 0; k4 < C_HID / 4; ++k4) {
        float w0 = Ws[(k4 * 4 + 0) * C_OUT + col];
        float w1 = Ws[(k4 * 4 + 1) * C_OUT + col];
        float w2 = Ws[(k4 * 4 + 2) * C_OUT + col];
        float w3 = Ws[(k4 * 4 + 3) * C_OUT + col];
        #pragma unroll
        for (int r = 0; r < 16; ++r) {
            float4 hv = Hsv[(rbase + r) * (C_HID / 4) + k4];
            acc[r] += hv.x * w0 + hv.y * w1 + hv.z * w2 + hv.w * w3;
        }
    }
    #pragma unroll
    for (int r = 0; r < 16; ++r) {
        int row = row0 + rbase + r;
        if (row < n) xws2_bf[(size_t)row * C_OUT + col] = f2bf(dinv[row] * acc[r]);
    }
}

// ---------- Aggregations (CSR gather of bf16 rows, f32 accumulate) ----------

// h_bf[i,c] = bf16(relu(d_i * (sum_s xws[s,c] + xws[i,c]) + b1[c]))
__global__ void agg1(const ushort_t* __restrict__ xws_bf, const float* __restrict__ dinv,
                     const int* __restrict__ offsets, const int* __restrict__ csr_src,
                     const float* __restrict__ b1, ushort_t* __restrict__ h_bf, int n) {
    int wid = threadIdx.x >> 6, lane = threadIdx.x & 63;
    float bias = b1[lane];
    for (int i = blockIdx.x * 4 + wid; i < n; i += gridDim.x * 4) {
        int beg = offsets[i], end = offsets[i + 1];
        float di = dinv[i];
        float acc = bf2f(xws_bf[(size_t)i * C_HID + lane]);  // self-loop term
        int k = beg;
        for (; k + 4 <= end; k += 4) {
            int s0 = csr_src[k], s1 = csr_src[k + 1];
            int s2 = csr_src[k + 2], s3 = csr_src[k + 3];
            float a0 = bf2f(xws_bf[(size_t)s0 * C_HID + lane]);
            float a1 = bf2f(xws_bf[(size_t)s1 * C_HID + lane]);
            float a2 = bf2f(xws_bf[(size_t)s2 * C_HID + lane]);
            float a3 = bf2f(xws_bf[(size_t)s3 * C_HID + lane]);
            acc += (a0 + a1) + (a2 + a3);
        }
        for (; k < end; ++k)
            acc += bf2f(xws_bf[(size_t)csr_src[k] * C_HID + lane]);
        h_bf[(size_t)i * C_HID + lane] = f2bf(fmaxf(di * acc + bias, 0.f));
    }
}

// out[i,c] = d_i * (sum_s xws2[s,c] + xws2[i,c]) + b2[c]; halves split edge list.
__global__ void agg2(const ushort_t* __restrict__ xws2_bf, const float* __restrict__ dinv,
                     const int* __restrict__ offsets, const int* __restrict__ csr_src,
                     const float* __restrict__ b2, float* __restrict__ out, int n) {
    int wid = threadIdx.x >> 6, lane = threadIdx.x & 63;
    int col = lane & 31, half = lane >> 5;
    float bias = b2[col];
    for (int i = blockIdx.x * 4 + wid; i < n; i += gridDim.x * 4) {
        int beg = offsets[i], end = offsets[i + 1];
        int len = end - beg;
        int hlen = (len + 1) >> 1;
        int kb = beg + half * hlen;
        int ke = half ? end : (beg + hlen);
        float di = dinv[i];
        float acc = half ? 0.f : bf2f(xws2_bf[(size_t)i * C_OUT + col]);
        int k = kb;
        for (; k + 4 <= ke; k += 4) {
            int s0 = csr_src[k], s1 = csr_src[k + 1];
            int s2 = csr_src[k + 2], s3 = csr_src[k + 3];
            float a0 = bf2f(xws2_bf[(size_t)s0 * C_OUT + col]);
            float a1 = bf2f(xws2_bf[(size_t)s1 * C_OUT + col]);
            float a2 = bf2f(xws2_bf[(size_t)s2 * C_OUT + col]);
            float a3 = bf2f(xws2_bf[(size_t)s3 * C_OUT + col]);
            acc += (a0 + a1) + (a2 + a3);
        }
        for (; k < ke; ++k)
            acc += bf2f(xws2_bf[(size_t)csr_src[k] * C_OUT + col]);
        acc += __shfl_xor(acc, 32, 64);
        if (half == 0)
            out[(size_t)i * C_OUT + col] = di * acc + bias;
    }
}

extern "C" void kernel_launch(void* const* d_in, const int* in_sizes, int n_in,
                              void* d_out, int out_size, void* d_ws, size_t ws_size,
                              hipStream_t stream) {
    const float* x  = (const float*)d_in[0];
    const int*   ei = (const int*)d_in[1];
    const float* W1 = (const float*)d_in[2];
    const float* b1 = (const float*)d_in[3];
    const float* W2 = (const float*)d_in[4];
    const float* b2 = (const float*)d_in[5];
    float* out = (float*)d_out;

    const int N = in_sizes[0] / C_IN;      // 100000
    const int E = in_sizes[1] / 2;         // 1600000
    const int* src = ei;
    const int* dst = ei + E;

    const int NB = (N + BK_NODES - 1) >> BK_SHIFT;          // 98
    const int CAP = (2 * (E / NB) + 1023) & ~1023;          // 32768 (2x mean)

    char* ws = (char*)d_ws;
    size_t off = 0;
    auto alloc = [&](size_t bytes) { char* p = ws + off; off += (bytes + 255) & ~(size_t)255; return p; };
    ushort_t* xw_bf  = (ushort_t*)alloc((size_t)N * C_HID * 2);  // xws1, reused as xws2
    ushort_t* h_bf   = (ushort_t*)alloc((size_t)N * C_HID * 2);
    int*   deg     = (int*)alloc((size_t)N * 4);
    float* dinv    = (float*)alloc((size_t)N * 4);
    int*   offsets = (int*)alloc((size_t)(N + 1) * 4);
    int*   cursor  = (int*)alloc((size_t)N * 4);
    int*   csr_src = (int*)alloc((size_t)E * 4);
    int*   bsums   = (int*)alloc(4096);
    int*   bcur    = (int*)alloc((size_t)BK_MAXB * 4);
    unsigned int* bucketed = (unsigned int*)alloc((size_t)NB * CAP * 4);
    bool use_bucket = (off <= ws_size) && (NB <= BK_MAXB) && (N < (1 << 17));

    const int nb1024 = (N + 1023) / 1024;  // 98

    if (use_bucket) {
        hipMemsetAsync(bcur, 0, (size_t)NB * 4, stream);
        bucket_edges<<<(E + EPB - 1) / EPB, 256, 0, stream>>>(
            src, dst, bcur, bucketed, CAP, E, NB);
        bucket_deg<<<NB, 1024, 0, stream>>>(bucketed, bcur, deg, CAP, N);
        scan_blocks<<<nb1024, 1024, 0, stream>>>(deg, offsets, bsums, dinv, N);
        scan_bsums<<<1, 1024, 0, stream>>>(bsums, nb1024);
        scan_add<<<nb1024, 1024, 0, stream>>>(offsets, bsums, N, E);
        fill_csr_bucketed<<<NB, 1024, 0, stream>>>(bucketed, bcur, offsets, csr_src, CAP, N);
    } else {
        hipMemsetAsync(deg, 0, (size_t)N * 4, stream);
        count_deg<<<2048, 256, 0, stream>>>(dst, deg, E);
        scan_blocks<<<nb1024, 1024, 0, stream>>>(deg, offsets, bsums, dinv, N);
        scan_bsums<<<1, 1024, 0, stream>>>(bsums, nb1024);
        scan_add<<<nb1024, 1024, 0, stream>>>(offsets, bsums, N, E);
        hipMemcpyAsync(cursor, offsets, (size_t)N * 4, hipMemcpyDeviceToDevice, stream);
        fill_csr<<<2048, 256, 0, stream>>>(src, dst, cursor, csr_src, E);
    }

    gemm1<<<(N + 63) / 64, 512, 0, stream>>>(x, W1, dinv, xw_bf, N);
    agg1<<<2048, 256, 0, stream>>>(xw_bf, dinv, offsets, csr_src, b1, h_bf, N);
    gemm2<<<(N + 127) / 128, 256, 0, stream>>>(h_bf, W2, dinv, xw_bf, N);
    agg2<<<2048, 256, 0, stream>>>(xw_bf, dinv, offsets, csr_src, b2, out, N);
}

// Round 7
// 176.971 us; speedup vs baseline: 3.4804x; 1.2825x over previous
//
#include <hip/hip_runtime.h>
#include <hip/hip_bf16.h>

// GCN 2-layer: x[N,128] @ W1[128,64] -> agg(+relu) -> @ W2[64,32] -> agg -> out[N,32]
// CSR-by-dst via 2-level counting sort (R4/R5). bf16 intermediates (R6).
// R7: gemm1 via MFMA 16x16x32 bf16 (f32 accum) -- R6 showed the f32 VALU GEMM is
// LDS-pipe-bound (12 LDS ops per 32 VALU ops). agg1/agg2 restructured for 2x/4x
// memory-level parallelism (multiple edges per wave, uint channel-pair loads).

#define C_IN  128
#define C_HID 64
#define C_OUT 32
#define BK_SHIFT 10
#define BK_NODES (1 << BK_SHIFT)
#define BK_MAXB  128
#define EPB 2048   // edges per bucket_edges block

typedef unsigned short ushort_t;
typedef __attribute__((ext_vector_type(8))) short bf16x8;
typedef __attribute__((ext_vector_type(4))) float f32x4;

__device__ inline ushort_t f2bf(float f) {
    __hip_bfloat16 b = __float2bfloat16(f);   // RNE
    return *reinterpret_cast<ushort_t*>(&b);
}
__device__ inline float bf2f(ushort_t u) {
    return __uint_as_float((unsigned int)u << 16);
}

// ---------- CSR build ----------

// Phase A: partition edges into 1024-node dst buckets, bucket-major packed.
__global__ __launch_bounds__(256) void bucket_edges(
        const int* __restrict__ src, const int* __restrict__ dst,
        int* __restrict__ bcur, unsigned int* __restrict__ bucketed,
        int cap, int E, int nb) {
    __shared__ unsigned int stage[EPB];
    __shared__ unsigned char bkt[EPB];
    __shared__ int cnt[BK_MAXB];
    __shared__ int lofs[BK_MAXB];
    __shared__ int base[BK_MAXB];
    int tid = threadIdx.x;
    for (int i = tid; i < nb; i += 256) cnt[i] = 0;
    __syncthreads();
    int e0 = blockIdx.x * EPB;
    int myb[8]; int myr[8]; unsigned int mys[8];
    #pragma unroll
    for (int i = 0; i < 8; ++i) {
        int e = e0 + i * 256 + tid;
        if (e < E) {
            int d = dst[e];
            int s = src[e];
            int b = d >> BK_SHIFT;
            myb[i] = b;
            mys[i] = (unsigned int)s | ((unsigned int)(d & (BK_NODES - 1)) << 17);
            myr[i] = atomicAdd(&cnt[b], 1);
        } else myb[i] = -1;
    }
    __syncthreads();
    if (tid < 64) {
        int b0 = 2 * tid, b1 = 2 * tid + 1;
        int c0 = (b0 < nb) ? cnt[b0] : 0;
        int c1 = (b1 < nb) ? cnt[b1] : 0;
        int p = c0 + c1;
        int s = p;
        #pragma unroll
        for (int off = 1; off < 64; off <<= 1) {
            int t = __shfl_up(s, off, 64);
            if (tid >= off) s += t;
        }
        if (b0 < nb) lofs[b0] = s - p;
        if (b1 < nb) lofs[b1] = s - c1;
    }
    __syncthreads();
    #pragma unroll
    for (int i = 0; i < 8; ++i) {
        if (myb[i] >= 0) {
            int p = lofs[myb[i]] + myr[i];
            stage[p] = mys[i];
            bkt[p] = (unsigned char)myb[i];
        }
    }
    for (int i = tid; i < nb; i += 256)
        base[i] = atomicAdd(&bcur[i], cnt[i]);
    __syncthreads();
    int total = min(EPB, E - e0);
    for (int p = tid; p < total; p += 256) {
        int b = bkt[p];
        int di = base[b] + (p - lofs[b]);
        if (di < cap)
            bucketed[(size_t)b * cap + di] = stage[p];
    }
}

// Phase B1: per-bucket degree histogram in LDS -> coalesced deg writes.
__global__ __launch_bounds__(1024) void bucket_deg(
        const unsigned int* __restrict__ bucketed, const int* __restrict__ bcur,
        int* __restrict__ deg, int cap, int n) {
    __shared__ int lcur[BK_NODES];
    int b = blockIdx.x;
    int node0 = b << BK_SHIFT;
    int nn = min(BK_NODES, n - node0);
    for (int j = threadIdx.x; j < BK_NODES; j += 1024) lcur[j] = 0;
    __syncthreads();
    int cnt = min(bcur[b], cap);
    const unsigned int* bp = bucketed + (size_t)b * cap;
    for (int e = threadIdx.x; e < cnt; e += 1024)
        atomicAdd(&lcur[bp[e] >> 17], 1);
    __syncthreads();
    for (int j = threadIdx.x; j < nn; j += 1024)
        deg[node0 + j] = lcur[j];
}

// Phase B2: one block per bucket; LDS node cursors; writes confined to window.
__global__ __launch_bounds__(1024) void fill_csr_bucketed(
        const unsigned int* __restrict__ bucketed, const int* __restrict__ bcur,
        const int* __restrict__ offsets, int* __restrict__ csr_src, int cap, int n) {
    __shared__ int lcur[BK_NODES];
    int b = blockIdx.x;
    int node0 = b << BK_SHIFT;
    int nn = min(BK_NODES, n - node0);
    for (int j = threadIdx.x; j < nn; j += 1024)
        lcur[j] = offsets[node0 + j];
    __syncthreads();
    int cnt = min(bcur[b], cap);
    const unsigned int* bp = bucketed + (size_t)b * cap;
    for (int e = threadIdx.x; e < cnt; e += 1024) {
        unsigned int v = bp[e];
        int pos = atomicAdd(&lcur[v >> 17], 1);
        csr_src[pos] = (int)(v & 0x1FFFFu);
    }
}

// fallback path kernels
__global__ void count_deg(const int* __restrict__ dst, int* __restrict__ deg, int E) {
    int idx = blockIdx.x * blockDim.x + threadIdx.x;
    int stride = gridDim.x * blockDim.x;
    for (int e = idx; e < E; e += stride)
        atomicAdd(&deg[dst[e]], 1);
}

__global__ void fill_csr(const int* __restrict__ src, const int* __restrict__ dst,
                         int* __restrict__ cursor, int* __restrict__ csr_src, int E) {
    int idx = blockIdx.x * blockDim.x + threadIdx.x;
    int stride = gridDim.x * blockDim.x;
    for (int e = idx; e < E; e += stride) {
        int pos = atomicAdd(&cursor[dst[e]], 1);
        csr_src[pos] = src[e];
    }
}

// block-level exclusive scan; also emits dinv = rsqrt(deg+1)
__global__ void scan_blocks(const int* __restrict__ deg, int* __restrict__ offsets,
                            int* __restrict__ bsums, float* __restrict__ dinv, int n) {
    __shared__ int wsum[16];
    int tid = threadIdx.x, lane = tid & 63, wid = tid >> 6;
    int i = blockIdx.x * 1024 + tid;
    int v = (i < n) ? deg[i] : 0;
    if (i < n) dinv[i] = rsqrtf((float)v + 1.0f);
    int s = v;
    #pragma unroll
    for (int off = 1; off < 64; off <<= 1) {
        int t = __shfl_up(s, off, 64);
        if (lane >= off) s += t;
    }
    if (lane == 63) wsum[wid] = s;
    __syncthreads();
    if (wid == 0 && lane < 16) {
        int ws = wsum[lane];
        #pragma unroll
        for (int off = 1; off < 16; off <<= 1) {
            int t = __shfl_up(ws, off, 64);
            if (lane >= off) ws += t;
        }
        wsum[lane] = ws;
        if (lane == 15) bsums[blockIdx.x] = ws;
    }
    __syncthreads();
    int wpre = (wid > 0) ? wsum[wid - 1] : 0;
    if (i < n) offsets[i] = wpre + s - v;
}

__global__ void scan_bsums(int* __restrict__ bsums, int nb) {
    __shared__ int wsum[16];
    int tid = threadIdx.x, lane = tid & 63, wid = tid >> 6;
    int v = (tid < nb) ? bsums[tid] : 0;
    int s = v;
    #pragma unroll
    for (int off = 1; off < 64; off <<= 1) {
        int t = __shfl_up(s, off, 64);
        if (lane >= off) s += t;
    }
    if (lane == 63) wsum[wid] = s;
    __syncthreads();
    if (wid == 0 && lane < 16) {
        int ws = wsum[lane];
        #pragma unroll
        for (int off = 1; off < 16; off <<= 1) {
            int t = __shfl_up(ws, off, 64);
            if (lane >= off) ws += t;
        }
        wsum[lane] = ws;
    }
    __syncthreads();
    int wpre = (wid > 0) ? wsum[wid - 1] : 0;
    if (tid < nb) bsums[tid] = wpre + s - v;
}

__global__ void scan_add(int* __restrict__ offsets, const int* __restrict__ bsums,
                         int n, int E) {
    int i = blockIdx.x * 1024 + threadIdx.x;
    if (i < n) offsets[i] += bsums[blockIdx.x];
    if (i == 0) offsets[n] = E;
}

// ---------- gemm1: x[N,128] @ W1[128,64] via MFMA bf16, f32 accum ----------
// 256 thr / 4 waves; 64-row tile. Wave w owns rows w*16..w*16+15.
// A-frag: lane holds Xs[rbase+(l&15)][kc*32+(l>>4)*8 + 0..7]  (b128 read)
// B-frag: Wl layout [kblk][col][j] -> lane reads Wl[kc*4+(l>>4)][cb*16+(l&15)][0..7]
// D: col = l&15 (in col-block), row = (l>>4)*4 + j   [m89-verified mapping]
__global__ __launch_bounds__(256) void gemm1_mfma(
        const float* __restrict__ x, const float* __restrict__ W1,
        const float* __restrict__ dinv, ushort_t* __restrict__ xws_bf, int n) {
    __shared__ ushort_t Xs[64 * 136];      // padded row stride 136 (17408 B)
    __shared__ ushort_t Wl[16 * 64 * 8];   // [kblk][col][j] (16384 B)
    int tid = threadIdx.x;
    // stage W1 -> bf16 swizzled
    {
        const float4* Wv = reinterpret_cast<const float4*>(W1);  // 2048 float4
        #pragma unroll
        for (int p = 0; p < 8; ++p) {
            int idx = p * 256 + tid;
            float4 w = Wv[idx];
            int k = idx >> 4;            // 16 float4 per k-row (64 cols)
            int c0 = (idx & 15) * 4;
            ushort_t* d = &Wl[(k >> 3) * 512 + c0 * 8 + (k & 7)];
            d[0]  = f2bf(w.x);
            d[8]  = f2bf(w.y);
            d[16] = f2bf(w.z);
            d[24] = f2bf(w.w);
        }
    }
    // stage x tile -> bf16 padded
    int row0 = blockIdx.x * 64;
    {
        const float4* xv = reinterpret_cast<const float4*>(x + (size_t)row0 * C_IN);
        int maxv = min(64, n - row0) * (C_IN / 4);
        #pragma unroll
        for (int p = 0; p < 8; ++p) {
            int idx = p * 256 + tid;
            float4 v = (idx < maxv) ? xv[idx] : float4{0.f, 0.f, 0.f, 0.f};
            int row = idx >> 5, k4 = idx & 31;
            ushort4 pk;
            pk.x = f2bf(v.x); pk.y = f2bf(v.y); pk.z = f2bf(v.z); pk.w = f2bf(v.w);
            *reinterpret_cast<ushort4*>(&Xs[row * 136 + k4 * 4]) = pk;
        }
    }
    __syncthreads();
    int wid = tid >> 6, lane = tid & 63;
    int rbase = wid * 16;
    int l15 = lane & 15, kgrp = lane >> 4;
    f32x4 acc0 = {0.f, 0.f, 0.f, 0.f}, acc1 = acc0, acc2 = acc0, acc3 = acc0;
    #pragma unroll
    for (int kc = 0; kc < 4; ++kc) {
        bf16x8 a = *reinterpret_cast<const bf16x8*>(&Xs[(rbase + l15) * 136 + kc * 32 + kgrp * 8]);
        const ushort_t* wb = &Wl[(kc * 4 + kgrp) * 512 + l15 * 8];
        bf16x8 b0 = *reinterpret_cast<const bf16x8*>(wb);
        bf16x8 b1 = *reinterpret_cast<const bf16x8*>(wb + 128);
        bf16x8 b2 = *reinterpret_cast<const bf16x8*>(wb + 256);
        bf16x8 b3 = *reinterpret_cast<const bf16x8*>(wb + 384);
        acc0 = __builtin_amdgcn_mfma_f32_16x16x32_bf16(a, b0, acc0, 0, 0, 0);
        acc1 = __builtin_amdgcn_mfma_f32_16x16x32_bf16(a, b1, acc1, 0, 0, 0);
        acc2 = __builtin_amdgcn_mfma_f32_16x16x32_bf16(a, b2, acc2, 0, 0, 0);
        acc3 = __builtin_amdgcn_mfma_f32_16x16x32_bf16(a, b3, acc3, 0, 0, 0);
    }
    // epilogue: D row = rbase + (l>>4)*4 + j, col = cb*16 + (l&15)
    #pragma unroll
    for (int j = 0; j < 4; ++j) {
        int row = row0 + rbase + kgrp * 4 + j;
        if (row < n) {
            float di = dinv[row];
            ushort_t* o = &xws_bf[(size_t)row * C_HID + l15];
            o[0]  = f2bf(di * acc0[j]);
            o[16] = f2bf(di * acc1[j]);
            o[32] = f2bf(di * acc2[j]);
            o[48] = f2bf(di * acc3[j]);
        }
    }
}

// ---------- gemm2 (f32 VALU, LDS-tiled; h bf16 in, xws2 bf16 out) ----------

__global__ __launch_bounds__(256) void gemm2(
        const ushort_t* __restrict__ h_bf, const float* __restrict__ W2,
        const float* __restrict__ dinv, ushort_t* __restrict__ xws2_bf, int n) {
    __shared__ float Ws[C_HID * C_OUT];  // 8 KiB
    __shared__ float Hs[128 * C_HID];    // 32 KiB
    int tid = threadIdx.x;
    {
        const float4* Wv = reinterpret_cast<const float4*>(W2);
        float4* Wsv = reinterpret_cast<float4*>(Ws);
        #pragma unroll
        for (int p = 0; p < (C_HID * C_OUT / 4) / 256; ++p)
            Wsv[p * 256 + tid] = Wv[p * 256 + tid];
    }
    int row0 = blockIdx.x * 128;
    {
        const uint4* hv = reinterpret_cast<const uint4*>(h_bf + (size_t)row0 * C_HID);
        float4* Hsv = reinterpret_cast<float4*>(Hs);
        int maxe = min(128, n - row0) * (C_HID / 8);
        #pragma unroll
        for (int p = 0; p < 4; ++p) {
            int idx = p * 256 + tid;
            uint4 raw = (idx < maxe) ? hv[idx] : uint4{0u, 0u, 0u, 0u};
            float4 lo, hi;
            lo.x = bf2f((ushort_t)(raw.x & 0xffffu)); lo.y = bf2f((ushort_t)(raw.x >> 16));
            lo.z = bf2f((ushort_t)(raw.y & 0xffffu)); lo.w = bf2f((ushort_t)(raw.y >> 16));
            hi.x = bf2f((ushort_t)(raw.z & 0xffffu)); hi.y = bf2f((ushort_t)(raw.z >> 16));
            hi.z = bf2f((ushort_t)(raw.w & 0xffffu)); hi.w = bf2f((ushort_t)(raw.w >> 16));
            Hsv[idx * 2] = lo;
            Hsv[idx * 2 + 1] = hi;
        }
    }
    __syncthreads();
    int wid = tid >> 6, lane = tid & 63;
    int col = lane & 31, rh = lane >> 5;
    int rbase = wid * 32 + rh * 16;
    float acc[16];
    #pragma unroll
    for (int r = 0; r < 16; ++r) acc[r] = 0.f;
    const float4* Hsv = reinterpret_cast<const float4*>(Hs);
    #pragma unroll 2
    for (int k4 = 0; k4 < C_HID / 4; ++k4) {
        float w0 = Ws[(k4 * 4 + 0) * C_OUT + col];
        float w1 = Ws[(k4 * 4 + 1) * C_OUT + col];
        float w2 = Ws[(k4 * 4 + 2) * C_OUT + col];
        float w3 = Ws[(k4 * 4 + 3) * C_OUT + col];
        #pragma unroll
        for (int r = 0; r < 16; ++r) {
            float4 hv = Hsv[(rbase + r) * (C_HID / 4) + k4];
            acc[r] += hv.x * w0 + hv.y * w1 + hv.z * w2 + hv.w * w3;
        }
    }
    #pragma unroll
    for (int r = 0; r < 16; ++r) {
        int row = row0 + rbase + r;
        if (row < n) xws2_bf[(size_t)row * C_OUT + col] = f2bf(dinv[row] * acc[r]);
    }
}

// ---------- Aggregations: multi-edge-per-wave gathers, f32 accumulate ----------

// agg1: 2 edges/wave step; lane = (p = lane>>5 edge slot, c2 = lane&31 chan pair)
__global__ void agg1(const ushort_t* __restrict__ xws_bf, const float* __restrict__ dinv,
                     const int* __restrict__ offsets, const int* __restrict__ csr_src,
                     const float* __restrict__ b1, ushort_t* __restrict__ h_bf, int n) {
    int wid = threadIdx.x >> 6, lane = threadIdx.x & 63;
    int p = lane >> 5, c2 = lane & 31;
    float2 bb = *reinterpret_cast<const float2*>(&b1[2 * c2]);
    for (int i = blockIdx.x * 4 + wid; i < n; i += gridDim.x * 4) {
        int beg = offsets[i], end = offsets[i + 1];
        float di = dinv[i];
        float a0 = 0.f, a1 = 0.f;
        if (p == 0) {   // self-loop term counted once
            unsigned int v = *reinterpret_cast<const unsigned int*>(
                &xws_bf[(size_t)i * C_HID + 2 * c2]);
            a0 = bf2f((ushort_t)(v & 0xffffu));
            a1 = bf2f((ushort_t)(v >> 16));
        }
        int k = beg;
        for (; k + 8 <= end; k += 8) {
            int s0 = csr_src[k + p];
            int s1 = csr_src[k + 2 + p];
            int s2 = csr_src[k + 4 + p];
            int s3 = csr_src[k + 6 + p];
            unsigned int v0 = *reinterpret_cast<const unsigned int*>(&xws_bf[(size_t)s0 * C_HID + 2 * c2]);
            unsigned int v1 = *reinterpret_cast<const unsigned int*>(&xws_bf[(size_t)s1 * C_HID + 2 * c2]);
            unsigned int v2 = *reinterpret_cast<const unsigned int*>(&xws_bf[(size_t)s2 * C_HID + 2 * c2]);
            unsigned int v3 = *reinterpret_cast<const unsigned int*>(&xws_bf[(size_t)s3 * C_HID + 2 * c2]);
            a0 += (bf2f((ushort_t)(v0 & 0xffffu)) + bf2f((ushort_t)(v1 & 0xffffu)))
                + (bf2f((ushort_t)(v2 & 0xffffu)) + bf2f((ushort_t)(v3 & 0xffffu)));
            a1 += (bf2f((ushort_t)(v0 >> 16)) + bf2f((ushort_t)(v1 >> 16)))
                + (bf2f((ushort_t)(v2 >> 16)) + bf2f((ushort_t)(v3 >> 16)));
        }
        for (; k + 2 <= end; k += 2) {
            int s = csr_src[k + p];
            unsigned int v = *reinterpret_cast<const unsigned int*>(&xws_bf[(size_t)s * C_HID + 2 * c2]);
            a0 += bf2f((ushort_t)(v & 0xffffu));
            a1 += bf2f((ushort_t)(v >> 16));
        }
        if (k < end && p == 0) {   // odd tail
            int s = csr_src[k];
            unsigned int v = *reinterpret_cast<const unsigned int*>(&xws_bf[(size_t)s * C_HID + 2 * c2]);
            a0 += bf2f((ushort_t)(v & 0xffffu));
            a1 += bf2f((ushort_t)(v >> 16));
        }
        a0 += __shfl_xor(a0, 32, 64);
        a1 += __shfl_xor(a1, 32, 64);
        if (p == 0) {
            float r0 = fmaxf(di * a0 + bb.x, 0.f);
            float r1 = fmaxf(di * a1 + bb.y, 0.f);
            unsigned int pk = (unsigned int)f2bf(r0) | ((unsigned int)f2bf(r1) << 16);
            *reinterpret_cast<unsigned int*>(&h_bf[(size_t)i * C_HID + 2 * c2]) = pk;
        }
    }
}

// agg2: 4 edges/wave step; lane = (q = lane>>4 edge slot, c2 = lane&15 chan pair)
__global__ void agg2(const ushort_t* __restrict__ xws2_bf, const float* __restrict__ dinv,
                     const int* __restrict__ offsets, const int* __restrict__ csr_src,
                     const float* __restrict__ b2, float* __restrict__ out, int n) {
    int wid = threadIdx.x >> 6, lane = threadIdx.x & 63;
    int q = lane >> 4, c2 = lane & 15;
    float2 bb = *reinterpret_cast<const float2*>(&b2[2 * c2]);
    for (int i = blockIdx.x * 4 + wid; i < n; i += gridDim.x * 4) {
        int beg = offsets[i], end = offsets[i + 1];
        float di = dinv[i];
        float a0 = 0.f, a1 = 0.f;
        if (q == 0) {
            unsigned int v = *reinterpret_cast<const unsigned int*>(
                &xws2_bf[(size_t)i * C_OUT + 2 * c2]);
            a0 = bf2f((ushort_t)(v & 0xffffu));
            a1 = bf2f((ushort_t)(v >> 16));
        }
        int k = beg;
        for (; k + 8 <= end; k += 8) {
            int s0 = csr_src[k + q];
            int s1 = csr_src[k + 4 + q];
            unsigned int v0 = *reinterpret_cast<const unsigned int*>(&xws2_bf[(size_t)s0 * C_OUT + 2 * c2]);
            unsigned int v1 = *reinterpret_cast<const unsigned int*>(&xws2_bf[(size_t)s1 * C_OUT + 2 * c2]);
            a0 += bf2f((ushort_t)(v0 & 0xffffu)) + bf2f((ushort_t)(v1 & 0xffffu));
            a1 += bf2f((ushort_t)(v0 >> 16)) + bf2f((ushort_t)(v1 >> 16));
        }
        for (; k + 4 <= end; k += 4) {
            int s = csr_src[k + q];
            unsigned int v = *reinterpret_cast<const unsigned int*>(&xws2_bf[(size_t)s * C_OUT + 2 * c2]);
            a0 += bf2f((ushort_t)(v & 0xffffu));
            a1 += bf2f((ushort_t)(v >> 16));
        }
        if (k + q < end) {   // tail 1..3 edges
            int s = csr_src[k + q];
            unsigned int v = *reinterpret_cast<const unsigned int*>(&xws2_bf[(size_t)s * C_OUT + 2 * c2]);
            a0 += bf2f((ushort_t)(v & 0xffffu));
            a1 += bf2f((ushort_t)(v >> 16));
        }
        a0 += __shfl_xor(a0, 32, 64);
        a0 += __shfl_xor(a0, 16, 64);
        a1 += __shfl_xor(a1, 32, 64);
        a1 += __shfl_xor(a1, 16, 64);
        if (q == 0) {
            float2 r;
            r.x = di * a0 + bb.x;
            r.y = di * a1 + bb.y;
            *reinterpret_cast<float2*>(&out[(size_t)i * C_OUT + 2 * c2]) = r;
        }
    }
}

extern "C" void kernel_launch(void* const* d_in, const int* in_sizes, int n_in,
                              void* d_out, int out_size, void* d_ws, size_t ws_size,
                              hipStream_t stream) {
    const float* x  = (const float*)d_in[0];
    const int*   ei = (const int*)d_in[1];
    const float* W1 = (const float*)d_in[2];
    const float* b1 = (const float*)d_in[3];
    const float* W2 = (const float*)d_in[4];
    const float* b2 = (const float*)d_in[5];
    float* out = (float*)d_out;

    const int N = in_sizes[0] / C_IN;      // 100000
    const int E = in_sizes[1] / 2;         // 1600000
    const int* src = ei;
    const int* dst = ei + E;

    const int NB = (N + BK_NODES - 1) >> BK_SHIFT;          // 98
    const int CAP = (2 * (E / NB) + 1023) & ~1023;          // 32768 (2x mean)

    char* ws = (char*)d_ws;
    size_t off = 0;
    auto alloc = [&](size_t bytes) { char* p = ws + off; off += (bytes + 255) & ~(size_t)255; return p; };
    ushort_t* xw_bf  = (ushort_t*)alloc((size_t)N * C_HID * 2);  // xws1, reused as xws2
    ushort_t* h_bf   = (ushort_t*)alloc((size_t)N * C_HID * 2);
    int*   deg     = (int*)alloc((size_t)N * 4);
    float* dinv    = (float*)alloc((size_t)N * 4);
    int*   offsets = (int*)alloc((size_t)(N + 1) * 4);
    int*   cursor  = (int*)alloc((size_t)N * 4);
    int*   csr_src = (int*)alloc((size_t)E * 4);
    int*   bsums   = (int*)alloc(4096);
    int*   bcur    = (int*)alloc((size_t)BK_MAXB * 4);
    unsigned int* bucketed = (unsigned int*)alloc((size_t)NB * CAP * 4);
    bool use_bucket = (off <= ws_size) && (NB <= BK_MAXB) && (N < (1 << 17));

    const int nb1024 = (N + 1023) / 1024;  // 98

    if (use_bucket) {
        hipMemsetAsync(bcur, 0, (size_t)NB * 4, stream);
        bucket_edges<<<(E + EPB - 1) / EPB, 256, 0, stream>>>(
            src, dst, bcur, bucketed, CAP, E, NB);
        bucket_deg<<<NB, 1024, 0, stream>>>(bucketed, bcur, deg, CAP, N);
        scan_blocks<<<nb1024, 1024, 0, stream>>>(deg, offsets, bsums, dinv, N);
        scan_bsums<<<1, 1024, 0, stream>>>(bsums, nb1024);
        scan_add<<<nb1024, 1024, 0, stream>>>(offsets, bsums, N, E);
        fill_csr_bucketed<<<NB, 1024, 0, stream>>>(bucketed, bcur, offsets, csr_src, CAP, N);
    } else {
        hipMemsetAsync(deg, 0, (size_t)N * 4, stream);
        count_deg<<<2048, 256, 0, stream>>>(dst, deg, E);
        scan_blocks<<<nb1024, 1024, 0, stream>>>(deg, offsets, bsums, dinv, N);
        scan_bsums<<<1, 1024, 0, stream>>>(bsums, nb1024);
        scan_add<<<nb1024, 1024, 0, stream>>>(offsets, bsums, N, E);
        hipMemcpyAsync(cursor, offsets, (size_t)N * 4, hipMemcpyDeviceToDevice, stream);
        fill_csr<<<2048, 256, 0, stream>>>(src, dst, cursor, csr_src, E);
    }

    gemm1_mfma<<<(N + 63) / 64, 256, 0, stream>>>(x, W1, dinv, xw_bf, N);
    agg1<<<2048, 256, 0, stream>>>(xw_bf, dinv, offsets, csr_src, b1, h_bf, N);
    gemm2<<<(N + 127) / 128, 256, 0, stream>>>(h_bf, W2, dinv, xw_bf, N);
    agg2<<<2048, 256, 0, stream>>>(xw_bf, dinv, offsets, csr_src, b2, out, N);
}